// Round 8
// baseline (437.521 us; speedup 1.0000x reference)
//
#include <hip/hip_runtime.h>

#define N_NODES 100000
#define FDIM 64
#define BROWS 128                               // rows per bucket
#define NBUCK ((N_NODES + BROWS - 1) / BROWS)   // 782
#define EDGES_PER_BLK 8192
#define BCAP 3072                               // LDS sort capacity (mean 2046, sd 45)

// ---------------- ws layout ----------------
// cnts   : off 0      NBUCK*nblk ints (per-(bucket,block) counts -> bases); dead after bin
// endoff : off 0      N_NODES ints (CSR row-end offsets; written by sort, AFTER cnts dies)
// bbase  : off 656 KB NBUCK+1 ints (bucket bases + sentinel)
// cvbin  : off 1 MB   n_edges int2 {col | rowlo<<20, float_bits(val)}
#define WS_BBASE_OFF (656u * 1024u)
#define WS_CV_OFF    (1024u * 1024u)

// ============ fallback (round-4 verified): fp32 HW atomics ============
__global__ __launch_bounds__(256) void spmm_atomic(
    const float* __restrict__ x, const int* __restrict__ erow,
    const int* __restrict__ ecol, const float* __restrict__ eval,
    float* __restrict__ out, int n_edges)
{
    int tid = blockIdx.x * 256 + threadIdx.x;
    int e = tid >> 4, l = tid & 15;
    if (e >= n_edges) return;
    int row = erow[e], col = ecol[e];
    float v = eval[e];
    const float4 xv = *reinterpret_cast<const float4*>(x + (size_t)col * FDIM + l * 4);
    float* dst = out + (size_t)row * FDIM + l * 4;
    unsafeAtomicAdd(dst + 0, v * xv.x);
    unsafeAtomicAdd(dst + 1, v * xv.y);
    unsafeAtomicAdd(dst + 2, v * xv.z);
    unsafeAtomicAdd(dst + 3, v * xv.w);
}

// ============ per-(bucket,block) counts: LDS hist, plain writes ============
__global__ __launch_bounds__(256) void count_blocks(
    const int* __restrict__ erow, int* __restrict__ cnts,
    int n_edges, int nblk)
{
    __shared__ int cnt[NBUCK];
    const int blk = blockIdx.x, t = threadIdx.x;
    for (int i = t; i < NBUCK; i += 256) cnt[i] = 0;
    __syncthreads();
    const int beg = blk * EDGES_PER_BLK;
    const int end = min(beg + EDGES_PER_BLK, n_edges);
    for (int i = beg + t; i < end; i += 256)
        atomicAdd(&cnt[erow[i] >> 7], 1);
    __syncthreads();
    for (int b = t; b < NBUCK; b += 256)
        cnts[b * nblk + blk] = cnt[b];
}

// ============ exclusive scan of all (bucket,block) counts (one block) ============
// cnts[] is bucket-major, block-minor; overwritten in place with exclusive bases.
// Also emits bbase[b] (= base of (b,0)) and the sentinel bbase[NBUCK]=n_edges.
__global__ __launch_bounds__(1024) void scan_all(
    int* __restrict__ cnts, int* __restrict__ bbase, int total, int nblk, int n_edges)
{
    __shared__ int ssum[1024];
    const int t = threadIdx.x;
    const int C = (total + 1023) >> 10;
    int s = 0;
    for (int k = 0; k < C; ++k) {
        int idx = t * C + k;
        if (idx < total) s += cnts[idx];
    }
    ssum[t] = s;
    __syncthreads();
    for (int off = 1; off < 1024; off <<= 1) {
        int v = (t >= off) ? ssum[t - off] : 0;
        __syncthreads();
        ssum[t] += v;
        __syncthreads();
    }
    int base = ssum[t] - s;      // exclusive prefix across threads
    for (int k = 0; k < C; ++k) {
        int idx = t * C + k;
        if (idx < total) {
            int c = cnts[idx];
            cnts[idx] = base;
            if (idx % nblk == 0) bbase[idx / nblk] = base;
            base += c;
        }
    }
    if (t == 0) bbase[NBUCK] = n_edges;
}

// ============ bin via block-private segments (LDS cursors, no global atomics) ============
__global__ __launch_bounds__(256) void bin_pass2(
    const int* __restrict__ erow, const int* __restrict__ ecol,
    const float* __restrict__ eval, const int* __restrict__ cnts,
    int2* __restrict__ cvbin, int n_edges, int nblk)
{
    __shared__ int cur[NBUCK];
    const int blk = blockIdx.x, t = threadIdx.x;
    for (int b = t; b < NBUCK; b += 256) cur[b] = cnts[b * nblk + blk];
    __syncthreads();
    const int beg = blk * EDGES_PER_BLK;
    const int end = min(beg + EDGES_PER_BLK, n_edges);
    for (int i = beg + t; i < end; i += 256) {
        int r = erow[i];
        int b = r >> 7;
        int pos = atomicAdd(&cur[b], 1);            // LDS atomic
        cvbin[pos] = make_int2(ecol[i] | ((r & 127) << 20), __float_as_int(eval[i]));
    }
}

// ============ per-bucket in-place counting sort (round-7 verified) ============
__global__ __launch_bounds__(256) void sort_bucket(
    const int* __restrict__ bbase, int2* __restrict__ cvbin,
    int* __restrict__ endoff)
{
    __shared__ int2 se[BCAP];        // 24 KB
    __shared__ int  hcnt[BROWS];
    __shared__ int  tmp[BROWS];
    __shared__ int  hoff[BROWS];
    const int b = blockIdx.x, t = threadIdx.x;
    const int beg = bbase[b];
    const int end = bbase[b + 1];
    const int n = end - beg;         // ~2046 +- 45 for this input; BCAP=3072

    for (int i = t; i < n; i += 256) se[i] = cvbin[beg + i];
    if (t < BROWS) hcnt[t] = 0;
    __syncthreads();

    for (int i = t; i < n; i += 256) atomicAdd(&hcnt[se[i].x >> 20], 1);
    __syncthreads();

    if (t < BROWS) tmp[t] = hcnt[t];
    __syncthreads();
    for (int off = 1; off < BROWS; off <<= 1) {
        int val = (t < BROWS && t >= off) ? tmp[t - off] : 0;
        __syncthreads();
        if (t < BROWS) tmp[t] += val;
        __syncthreads();
    }
    if (t < BROWS) hoff[t] = tmp[t] - hcnt[t];
    __syncthreads();

    for (int i = t; i < n; i += 256) {
        int2 e = se[i];
        int pos = atomicAdd(&hoff[e.x >> 20], 1);
        cvbin[beg + pos] = e;
    }
    __syncthreads();

    if (t < BROWS) {
        int row = b * BROWS + t;
        if (row < N_NODES) endoff[row] = beg + hoff[t];
    }
}

// ============ SpMM over CSR: one wave per row (round-5/7 verified) ============
__global__ __launch_bounds__(256) void spmm_csr(
    const float* __restrict__ x, const int* __restrict__ endoff,
    const int2* __restrict__ cv, float* __restrict__ out)
{
    const int wave = (blockIdx.x * 256 + threadIdx.x) >> 6;
    if (wave >= N_NODES) return;
    const int lane = threadIdx.x & 63;
    const int sub = lane >> 4, l = lane & 15;
    const int r = wave;
    const int beg = (r == 0) ? 0 : endoff[r - 1];
    const int end = endoff[r];

    float4 acc = {0.f, 0.f, 0.f, 0.f};
    for (int it = beg + sub; it < end; it += 4) {
        const int2 e = cv[it];
        const float v = __int_as_float(e.y);
        const int col = e.x & 0xFFFFF;
        const float4 xv = *reinterpret_cast<const float4*>(x + (size_t)col * FDIM + l * 4);
        acc.x += v * xv.x; acc.y += v * xv.y; acc.z += v * xv.z; acc.w += v * xv.w;
    }
    #pragma unroll
    for (int off = 16; off < 64; off <<= 1) {
        acc.x += __shfl_xor(acc.x, off);
        acc.y += __shfl_xor(acc.y, off);
        acc.z += __shfl_xor(acc.z, off);
        acc.w += __shfl_xor(acc.w, off);
    }
    if (sub == 0)
        *reinterpret_cast<float4*>(out + (size_t)r * FDIM + l * 4) = acc;
}

// ============ GEMM + bias + L2 normalize (verified) ============
__global__ __launch_bounds__(256) void gemm_norm(
    float* __restrict__ io, const float* __restrict__ W,
    const float* __restrict__ bias)
{
    __shared__ float4 Wl[64][16];
    __shared__ float4 bl[16];
    __shared__ float  s[4][4][68];

    const int t = threadIdx.x;
    for (int i = t; i < 64 * 16; i += 256)
        ((float4*)Wl)[i] = ((const float4*)W)[i];
    if (t < 16) bl[t] = ((const float4*)bias)[t];

    const int wid  = t >> 6;
    const int lane = t & 63;
    const int sub  = lane >> 4;
    const int l    = lane & 15;
    const long base = (long)blockIdx.x * 16 + wid * 4;

    float4 sv = *reinterpret_cast<const float4*>(io + base * FDIM + lane * 4);
    *reinterpret_cast<float4*>(&s[wid][lane >> 4][(lane & 15) * 4]) = sv;
    __syncthreads();

    float4 acc = {0.f, 0.f, 0.f, 0.f};
    const float* srow = s[wid][sub];
    #pragma unroll
    for (int k = 0; k < FDIM; ++k) {
        const float a = srow[k];
        const float4 w = Wl[k][l];
        acc.x += a * w.x; acc.y += a * w.y; acc.z += a * w.z; acc.w += a * w.w;
    }
    const float4 b = bl[l];
    acc.x += b.x; acc.y += b.y; acc.z += b.z; acc.w += b.w;

    float p = acc.x*acc.x + acc.y*acc.y + acc.z*acc.z + acc.w*acc.w;
    #pragma unroll
    for (int off = 1; off < 16; off <<= 1)
        p += __shfl_xor(p, off);
    const float inv = 1.0f / sqrtf(p);
    acc.x *= inv; acc.y *= inv; acc.z *= inv; acc.w *= inv;

    *reinterpret_cast<float4*>(io + (base + sub) * FDIM + l * 4) = acc;
}

extern "C" void kernel_launch(void* const* d_in, const int* in_sizes, int n_in,
                              void* d_out, int out_size, void* d_ws, size_t ws_size,
                              hipStream_t stream) {
    const float* x    = (const float*)d_in[0];
    const int*   erow = (const int*)d_in[1];
    const int*   ecol = (const int*)d_in[2];
    const float* eval = (const float*)d_in[3];
    const float* W    = (const float*)d_in[4];
    const float* bias = (const float*)d_in[5];
    float* out = (float*)d_out;
    const int n_edges = in_sizes[1];

    const int nblk = (n_edges + EDGES_PER_BLK - 1) / EDGES_PER_BLK;   // 196
    const size_t need = (size_t)WS_CV_OFF + (size_t)n_edges * sizeof(int2);
    const bool cnts_fit = (size_t)NBUCK * nblk * sizeof(int) <= WS_BBASE_OFF;

    if (ws_size >= need && cnts_fit) {
        int*  cnts   = (int*)d_ws;                              // dies after bin_pass2
        int*  endoff = (int*)d_ws;                              // born in sort_bucket
        int*  bbase  = (int*)((char*)d_ws + WS_BBASE_OFF);
        int2* cvbin  = (int2*)((char*)d_ws + WS_CV_OFF);

        count_blocks<<<nblk, 256, 0, stream>>>(erow, cnts, n_edges, nblk);
        scan_all<<<1, 1024, 0, stream>>>(cnts, bbase, NBUCK * nblk, nblk, n_edges);
        bin_pass2<<<nblk, 256, 0, stream>>>(erow, ecol, eval, cnts, cvbin, n_edges, nblk);
        sort_bucket<<<NBUCK, 256, 0, stream>>>(bbase, cvbin, endoff);
        spmm_csr<<<(N_NODES + 3) / 4, 256, 0, stream>>>(x, endoff, cvbin, out);
    } else {
        hipMemsetAsync(out, 0, (size_t)N_NODES * FDIM * sizeof(float), stream);
        long threads = (long)n_edges * 16;
        spmm_atomic<<<(int)((threads + 255) / 256), 256, 0, stream>>>(
            x, erow, ecol, eval, out, n_edges);
    }

    gemm_norm<<<N_NODES / 16, 256, 0, stream>>>(out, W, bias);
}

// Round 9
// 146.790 us; speedup vs baseline: 2.9806x; 2.9806x over previous
//
#include <hip/hip_runtime.h>

#define N_NODES 100000
#define FDIM 64
#define BROWS 128                               // rows per bucket
#define NBUCK ((N_NODES + BROWS - 1) / BROWS)   // 782
#define EDGES_PER_BLK 8192
#define BCAP 3072                               // LDS sort capacity (mean 2046, sd 45)

// ---------------- ws layout ----------------
// cnts   : off 0       NBUCK*nblk ints (within-bucket exclusive prefixes); dead after bin
// endoff : off 0       N_NODES ints (CSR row-end offsets; born in sort_bucket after cnts dies)
// bbase  : off 656 KB  NBUCK+1 ints (bucket bases + sentinel)
// btot   : off 672 KB  NBUCK ints (bucket totals)
// cvbin  : off 1 MB    n_edges int2 {col | rowlo<<20, float_bits(val)}
#define WS_BBASE_OFF (656u * 1024u)
#define WS_BTOT_OFF  (672u * 1024u)
#define WS_CV_OFF    (1024u * 1024u)

// ============ fallback (round-4 verified): fp32 HW atomics ============
__global__ __launch_bounds__(256) void spmm_atomic(
    const float* __restrict__ x, const int* __restrict__ erow,
    const int* __restrict__ ecol, const float* __restrict__ eval,
    float* __restrict__ out, int n_edges)
{
    int tid = blockIdx.x * 256 + threadIdx.x;
    int e = tid >> 4, l = tid & 15;
    if (e >= n_edges) return;
    int row = erow[e], col = ecol[e];
    float v = eval[e];
    const float4 xv = *reinterpret_cast<const float4*>(x + (size_t)col * FDIM + l * 4);
    float* dst = out + (size_t)row * FDIM + l * 4;
    unsafeAtomicAdd(dst + 0, v * xv.x);
    unsafeAtomicAdd(dst + 1, v * xv.y);
    unsafeAtomicAdd(dst + 2, v * xv.z);
    unsafeAtomicAdd(dst + 3, v * xv.w);
}

// ============ per-(bucket,block) counts: LDS hist, plain writes (round-8 verified) ============
__global__ __launch_bounds__(256) void count_blocks(
    const int* __restrict__ erow, int* __restrict__ cnts,
    int n_edges, int nblk)
{
    __shared__ int cnt[NBUCK];
    const int blk = blockIdx.x, t = threadIdx.x;
    for (int i = t; i < NBUCK; i += 256) cnt[i] = 0;
    __syncthreads();
    const int beg = blk * EDGES_PER_BLK;
    const int end = min(beg + EDGES_PER_BLK, n_edges);
    for (int i = beg + t; i < end; i += 256)
        atomicAdd(&cnt[erow[i] >> 7], 1);
    __syncthreads();
    for (int b = t; b < NBUCK; b += 256)
        cnts[b * nblk + blk] = cnt[b];
}

// ============ within-bucket exclusive scan (782 blocks, parallel) ============
// cnts[b*nblk .. b*nblk+nblk) -> exclusive prefix within bucket; btot[b] = total.
__global__ __launch_bounds__(256) void scan_within_bucket(
    int* __restrict__ cnts, int* __restrict__ btot, int nblk)
{
    __shared__ int ssum[256];
    const int b = blockIdx.x, t = threadIdx.x;
    const int c = (t < nblk) ? cnts[b * nblk + t] : 0;
    ssum[t] = c;
    __syncthreads();
    for (int off = 1; off < 256; off <<= 1) {
        int v = (t >= off) ? ssum[t - off] : 0;
        __syncthreads();
        ssum[t] += v;
        __syncthreads();
    }
    if (t < nblk) cnts[b * nblk + t] = ssum[t] - c;   // exclusive
    if (t == 255) btot[b] = ssum[255];
}

// ============ scan of bucket totals -> bbase (1 block; 782 elems, 1/thread) ============
__global__ __launch_bounds__(1024) void scan_btot(
    const int* __restrict__ btot, int* __restrict__ bbase, int n_edges)
{
    __shared__ int ssum[1024];
    const int t = threadIdx.x;
    const int v0 = (t < NBUCK) ? btot[t] : 0;
    ssum[t] = v0;
    __syncthreads();
    for (int off = 1; off < 1024; off <<= 1) {
        int v = (t >= off) ? ssum[t - off] : 0;
        __syncthreads();
        ssum[t] += v;
        __syncthreads();
    }
    if (t < NBUCK) bbase[t] = ssum[t] - v0;   // exclusive
    if (t == 0) bbase[NBUCK] = n_edges;       // sentinel
}

// ============ bin via block-private segments (LDS cursors; round-8 verified) ============
__global__ __launch_bounds__(256) void bin_pass2(
    const int* __restrict__ erow, const int* __restrict__ ecol,
    const float* __restrict__ eval, const int* __restrict__ cnts,
    const int* __restrict__ bbase, int2* __restrict__ cvbin,
    int n_edges, int nblk)
{
    __shared__ int cur[NBUCK];
    const int blk = blockIdx.x, t = threadIdx.x;
    for (int b = t; b < NBUCK; b += 256)
        cur[b] = bbase[b] + cnts[b * nblk + blk];
    __syncthreads();
    const int beg = blk * EDGES_PER_BLK;
    const int end = min(beg + EDGES_PER_BLK, n_edges);
    for (int i = beg + t; i < end; i += 256) {
        int r = erow[i];
        int b = r >> 7;
        int pos = atomicAdd(&cur[b], 1);            // LDS atomic
        cvbin[pos] = make_int2(ecol[i] | ((r & 127) << 20), __float_as_int(eval[i]));
    }
}

// ============ per-bucket in-place counting sort (round-7/8 verified) ============
__global__ __launch_bounds__(256) void sort_bucket(
    const int* __restrict__ bbase, int2* __restrict__ cvbin,
    int* __restrict__ endoff)
{
    __shared__ int2 se[BCAP];        // 24 KB
    __shared__ int  hcnt[BROWS];
    __shared__ int  tmp[BROWS];
    __shared__ int  hoff[BROWS];
    const int b = blockIdx.x, t = threadIdx.x;
    const int beg = bbase[b];
    const int end = bbase[b + 1];
    const int n = end - beg;         // ~2046 +- 45 for this input; BCAP=3072

    for (int i = t; i < n; i += 256) se[i] = cvbin[beg + i];
    if (t < BROWS) hcnt[t] = 0;
    __syncthreads();

    for (int i = t; i < n; i += 256) atomicAdd(&hcnt[se[i].x >> 20], 1);
    __syncthreads();

    if (t < BROWS) tmp[t] = hcnt[t];
    __syncthreads();
    for (int off = 1; off < BROWS; off <<= 1) {
        int val = (t < BROWS && t >= off) ? tmp[t - off] : 0;
        __syncthreads();
        if (t < BROWS) tmp[t] += val;
        __syncthreads();
    }
    if (t < BROWS) hoff[t] = tmp[t] - hcnt[t];
    __syncthreads();

    for (int i = t; i < n; i += 256) {
        int2 e = se[i];
        int pos = atomicAdd(&hoff[e.x >> 20], 1);
        cvbin[beg + pos] = e;
    }
    __syncthreads();

    if (t < BROWS) {
        int row = b * BROWS + t;
        if (row < N_NODES) endoff[row] = beg + hoff[t];
    }
}

// ============ SpMM over CSR: one wave per row (round-5/7 verified) ============
__global__ __launch_bounds__(256) void spmm_csr(
    const float* __restrict__ x, const int* __restrict__ endoff,
    const int2* __restrict__ cv, float* __restrict__ out)
{
    const int wave = (blockIdx.x * 256 + threadIdx.x) >> 6;
    if (wave >= N_NODES) return;
    const int lane = threadIdx.x & 63;
    const int sub = lane >> 4, l = lane & 15;
    const int r = wave;
    const int beg = (r == 0) ? 0 : endoff[r - 1];
    const int end = endoff[r];

    float4 acc = {0.f, 0.f, 0.f, 0.f};
    for (int it = beg + sub; it < end; it += 4) {
        const int2 e = cv[it];
        const float v = __int_as_float(e.y);
        const int col = e.x & 0xFFFFF;
        const float4 xv = *reinterpret_cast<const float4*>(x + (size_t)col * FDIM + l * 4);
        acc.x += v * xv.x; acc.y += v * xv.y; acc.z += v * xv.z; acc.w += v * xv.w;
    }
    #pragma unroll
    for (int off = 16; off < 64; off <<= 1) {
        acc.x += __shfl_xor(acc.x, off);
        acc.y += __shfl_xor(acc.y, off);
        acc.z += __shfl_xor(acc.z, off);
        acc.w += __shfl_xor(acc.w, off);
    }
    if (sub == 0)
        *reinterpret_cast<float4*>(out + (size_t)r * FDIM + l * 4) = acc;
}

// ============ GEMM + bias + L2 normalize (verified) ============
__global__ __launch_bounds__(256) void gemm_norm(
    float* __restrict__ io, const float* __restrict__ W,
    const float* __restrict__ bias)
{
    __shared__ float4 Wl[64][16];
    __shared__ float4 bl[16];
    __shared__ float  s[4][4][68];

    const int t = threadIdx.x;
    for (int i = t; i < 64 * 16; i += 256)
        ((float4*)Wl)[i] = ((const float4*)W)[i];
    if (t < 16) bl[t] = ((const float4*)bias)[t];

    const int wid  = t >> 6;
    const int lane = t & 63;
    const int sub  = lane >> 4;
    const int l    = lane & 15;
    const long base = (long)blockIdx.x * 16 + wid * 4;

    float4 sv = *reinterpret_cast<const float4*>(io + base * FDIM + lane * 4);
    *reinterpret_cast<float4*>(&s[wid][lane >> 4][(lane & 15) * 4]) = sv;
    __syncthreads();

    float4 acc = {0.f, 0.f, 0.f, 0.f};
    const float* srow = s[wid][sub];
    #pragma unroll
    for (int k = 0; k < FDIM; ++k) {
        const float a = srow[k];
        const float4 w = Wl[k][l];
        acc.x += a * w.x; acc.y += a * w.y; acc.z += a * w.z; acc.w += a * w.w;
    }
    const float4 b = bl[l];
    acc.x += b.x; acc.y += b.y; acc.z += b.z; acc.w += b.w;

    float p = acc.x*acc.x + acc.y*acc.y + acc.z*acc.z + acc.w*acc.w;
    #pragma unroll
    for (int off = 1; off < 16; off <<= 1)
        p += __shfl_xor(p, off);
    const float inv = 1.0f / sqrtf(p);
    acc.x *= inv; acc.y *= inv; acc.z *= inv; acc.w *= inv;

    *reinterpret_cast<float4*>(io + (base + sub) * FDIM + l * 4) = acc;
}

extern "C" void kernel_launch(void* const* d_in, const int* in_sizes, int n_in,
                              void* d_out, int out_size, void* d_ws, size_t ws_size,
                              hipStream_t stream) {
    const float* x    = (const float*)d_in[0];
    const int*   erow = (const int*)d_in[1];
    const int*   ecol = (const int*)d_in[2];
    const float* eval = (const float*)d_in[3];
    const float* W    = (const float*)d_in[4];
    const float* bias = (const float*)d_in[5];
    float* out = (float*)d_out;
    const int n_edges = in_sizes[1];

    const int nblk = (n_edges + EDGES_PER_BLK - 1) / EDGES_PER_BLK;   // 196
    const size_t need = (size_t)WS_CV_OFF + (size_t)n_edges * sizeof(int2);
    const bool cnts_fit =
        (size_t)NBUCK * nblk * sizeof(int) <= WS_BBASE_OFF && nblk <= 256;

    if (ws_size >= need && cnts_fit) {
        int*  cnts   = (int*)d_ws;                              // dies after bin_pass2
        int*  endoff = (int*)d_ws;                              // born in sort_bucket
        int*  bbase  = (int*)((char*)d_ws + WS_BBASE_OFF);
        int*  btot   = (int*)((char*)d_ws + WS_BTOT_OFF);
        int2* cvbin  = (int2*)((char*)d_ws + WS_CV_OFF);

        count_blocks<<<nblk, 256, 0, stream>>>(erow, cnts, n_edges, nblk);
        scan_within_bucket<<<NBUCK, 256, 0, stream>>>(cnts, btot, nblk);
        scan_btot<<<1, 1024, 0, stream>>>(btot, bbase, n_edges);
        bin_pass2<<<nblk, 256, 0, stream>>>(erow, ecol, eval, cnts, bbase, cvbin,
                                            n_edges, nblk);
        sort_bucket<<<NBUCK, 256, 0, stream>>>(bbase, cvbin, endoff);
        spmm_csr<<<(N_NODES + 3) / 4, 256, 0, stream>>>(x, endoff, cvbin, out);
    } else {
        hipMemsetAsync(out, 0, (size_t)N_NODES * FDIM * sizeof(float), stream);
        long threads = (long)n_edges * 16;
        spmm_atomic<<<(int)((threads + 255) / 256), 256, 0, stream>>>(
            x, erow, ecol, eval, out, n_edges);
    }

    gemm_norm<<<N_NODES / 16, 256, 0, stream>>>(out, W, bias);
}

// Round 10
// 140.003 us; speedup vs baseline: 3.1251x; 1.0485x over previous
//
#include <hip/hip_runtime.h>

#define N_NODES 100000
#define FDIM 64
#define BROWS 128                               // rows per bucket
#define NBUCK ((N_NODES + BROWS - 1) / BROWS)   // 782
#define EDGES_PER_BLK 8192
#define BCAP 3072                               // LDS sort capacity (mean 2046, sd 45)

// ---------------- ws layout ----------------
// cnts   : off 0       NBUCK*nblk ints (within-bucket exclusive prefixes); dead after bin
// endoff : off 0       N_NODES ints (CSR row-end offsets; born in sort_bucket after cnts dies)
// bbase  : off 656 KB  NBUCK+1 ints (bucket bases + sentinel)
// btot   : off 672 KB  NBUCK ints (bucket totals)
// cvbin  : off 1 MB    n_edges int2 {col | rowlo<<20, float_bits(val)}
#define WS_BBASE_OFF (656u * 1024u)
#define WS_BTOT_OFF  (672u * 1024u)
#define WS_CV_OFF    (1024u * 1024u)

// ============ fallback (round-4 verified): fp32 HW atomics ============
__global__ __launch_bounds__(256) void spmm_atomic(
    const float* __restrict__ x, const int* __restrict__ erow,
    const int* __restrict__ ecol, const float* __restrict__ eval,
    float* __restrict__ out, int n_edges)
{
    int tid = blockIdx.x * 256 + threadIdx.x;
    int e = tid >> 4, l = tid & 15;
    if (e >= n_edges) return;
    int row = erow[e], col = ecol[e];
    float v = eval[e];
    const float4 xv = *reinterpret_cast<const float4*>(x + (size_t)col * FDIM + l * 4);
    float* dst = out + (size_t)row * FDIM + l * 4;
    unsafeAtomicAdd(dst + 0, v * xv.x);
    unsafeAtomicAdd(dst + 1, v * xv.y);
    unsafeAtomicAdd(dst + 2, v * xv.z);
    unsafeAtomicAdd(dst + 3, v * xv.w);
}

// ============ per-(bucket,block) counts: LDS hist, plain writes (round-8 verified) ============
__global__ __launch_bounds__(256) void count_blocks(
    const int* __restrict__ erow, int* __restrict__ cnts,
    int n_edges, int nblk)
{
    __shared__ int cnt[NBUCK];
    const int blk = blockIdx.x, t = threadIdx.x;
    for (int i = t; i < NBUCK; i += 256) cnt[i] = 0;
    __syncthreads();
    const int beg = blk * EDGES_PER_BLK;
    const int end = min(beg + EDGES_PER_BLK, n_edges);
    for (int i = beg + t; i < end; i += 256)
        atomicAdd(&cnt[erow[i] >> 7], 1);
    __syncthreads();
    for (int b = t; b < NBUCK; b += 256)
        cnts[b * nblk + blk] = cnt[b];
}

// ============ within-bucket exclusive scan (782 blocks; round-9 verified) ============
__global__ __launch_bounds__(256) void scan_within_bucket(
    int* __restrict__ cnts, int* __restrict__ btot, int nblk)
{
    __shared__ int ssum[256];
    const int b = blockIdx.x, t = threadIdx.x;
    const int c = (t < nblk) ? cnts[b * nblk + t] : 0;
    ssum[t] = c;
    __syncthreads();
    for (int off = 1; off < 256; off <<= 1) {
        int v = (t >= off) ? ssum[t - off] : 0;
        __syncthreads();
        ssum[t] += v;
        __syncthreads();
    }
    if (t < nblk) cnts[b * nblk + t] = ssum[t] - c;   // exclusive
    if (t == 255) btot[b] = ssum[255];
}

// ============ scan of bucket totals -> bbase (round-9 verified) ============
__global__ __launch_bounds__(1024) void scan_btot(
    const int* __restrict__ btot, int* __restrict__ bbase, int n_edges)
{
    __shared__ int ssum[1024];
    const int t = threadIdx.x;
    const int v0 = (t < NBUCK) ? btot[t] : 0;
    ssum[t] = v0;
    __syncthreads();
    for (int off = 1; off < 1024; off <<= 1) {
        int v = (t >= off) ? ssum[t - off] : 0;
        __syncthreads();
        ssum[t] += v;
        __syncthreads();
    }
    if (t < NBUCK) bbase[t] = ssum[t] - v0;   // exclusive
    if (t == 0) bbase[NBUCK] = n_edges;       // sentinel
}

// ============ bin via block-private segments (LDS cursors; round-9 verified) ============
__global__ __launch_bounds__(256) void bin_pass2(
    const int* __restrict__ erow, const int* __restrict__ ecol,
    const float* __restrict__ eval, const int* __restrict__ cnts,
    const int* __restrict__ bbase, int2* __restrict__ cvbin,
    int n_edges, int nblk)
{
    __shared__ int cur[NBUCK];
    const int blk = blockIdx.x, t = threadIdx.x;
    for (int b = t; b < NBUCK; b += 256)
        cur[b] = bbase[b] + cnts[b * nblk + blk];
    __syncthreads();
    const int beg = blk * EDGES_PER_BLK;
    const int end = min(beg + EDGES_PER_BLK, n_edges);
    for (int i = beg + t; i < end; i += 256) {
        int r = erow[i];
        int b = r >> 7;
        int pos = atomicAdd(&cur[b], 1);            // LDS atomic
        cvbin[pos] = make_int2(ecol[i] | ((r & 127) << 20), __float_as_int(eval[i]));
    }
}

// ============ per-bucket in-place counting sort (round-7/8/9 verified) ============
__global__ __launch_bounds__(256) void sort_bucket(
    const int* __restrict__ bbase, int2* __restrict__ cvbin,
    int* __restrict__ endoff)
{
    __shared__ int2 se[BCAP];        // 24 KB
    __shared__ int  hcnt[BROWS];
    __shared__ int  tmp[BROWS];
    __shared__ int  hoff[BROWS];
    const int b = blockIdx.x, t = threadIdx.x;
    const int beg = bbase[b];
    const int end = bbase[b + 1];
    const int n = end - beg;         // ~2046 +- 45 for this input; BCAP=3072

    for (int i = t; i < n; i += 256) se[i] = cvbin[beg + i];
    if (t < BROWS) hcnt[t] = 0;
    __syncthreads();

    for (int i = t; i < n; i += 256) atomicAdd(&hcnt[se[i].x >> 20], 1);
    __syncthreads();

    if (t < BROWS) tmp[t] = hcnt[t];
    __syncthreads();
    for (int off = 1; off < BROWS; off <<= 1) {
        int val = (t < BROWS && t >= off) ? tmp[t - off] : 0;
        __syncthreads();
        if (t < BROWS) tmp[t] += val;
        __syncthreads();
    }
    if (t < BROWS) hoff[t] = tmp[t] - hcnt[t];
    __syncthreads();

    for (int i = t; i < n; i += 256) {
        int2 e = se[i];
        int pos = atomicAdd(&hoff[e.x >> 20], 1);
        cvbin[beg + pos] = e;
    }
    __syncthreads();

    if (t < BROWS) {
        int row = b * BROWS + t;
        if (row < N_NODES) endoff[row] = beg + hoff[t];
    }
}

// ============ SpMM over CSR: one wave per row, 4-way unrolled gathers ============
// 16-lane sub-groups; sub keeps 4 independent edge streams in flight
// (16 outstanding gathers per wave, vs 4 in round 9's latency-bound version).
__global__ __launch_bounds__(256) void spmm_csr(
    const float* __restrict__ x, const int* __restrict__ endoff,
    const int2* __restrict__ cv, float* __restrict__ out)
{
    const int wave = (blockIdx.x * 256 + threadIdx.x) >> 6;
    if (wave >= N_NODES) return;
    const int lane = threadIdx.x & 63;
    const int sub = lane >> 4, l = lane & 15;
    const int r = wave;
    const int beg = (r == 0) ? 0 : endoff[r - 1];
    const int end = endoff[r];

    float4 acc = {0.f, 0.f, 0.f, 0.f};
    int it = beg + sub;

    // 4-way unrolled main loop: 4 independent cv loads + 4 independent gathers
    for (; it + 12 < end; it += 16) {
        const int2 ea = cv[it];
        const int2 eb = cv[it + 4];
        const int2 ec = cv[it + 8];
        const int2 ed = cv[it + 12];
        const float4 xa = *reinterpret_cast<const float4*>(x + (size_t)(ea.x & 0xFFFFF) * FDIM + l * 4);
        const float4 xb = *reinterpret_cast<const float4*>(x + (size_t)(eb.x & 0xFFFFF) * FDIM + l * 4);
        const float4 xc = *reinterpret_cast<const float4*>(x + (size_t)(ec.x & 0xFFFFF) * FDIM + l * 4);
        const float4 xd = *reinterpret_cast<const float4*>(x + (size_t)(ed.x & 0xFFFFF) * FDIM + l * 4);
        const float va = __int_as_float(ea.y);
        const float vb = __int_as_float(eb.y);
        const float vc = __int_as_float(ec.y);
        const float vd = __int_as_float(ed.y);
        acc.x += va * xa.x; acc.y += va * xa.y; acc.z += va * xa.z; acc.w += va * xa.w;
        acc.x += vb * xb.x; acc.y += vb * xb.y; acc.z += vb * xb.z; acc.w += vb * xb.w;
        acc.x += vc * xc.x; acc.y += vc * xc.y; acc.z += vc * xc.z; acc.w += vc * xc.w;
        acc.x += vd * xd.x; acc.y += vd * xd.y; acc.z += vd * xd.z; acc.w += vd * xd.w;
    }
    // remainder
    for (; it < end; it += 4) {
        const int2 e = cv[it];
        const float v = __int_as_float(e.y);
        const float4 xv = *reinterpret_cast<const float4*>(x + (size_t)(e.x & 0xFFFFF) * FDIM + l * 4);
        acc.x += v * xv.x; acc.y += v * xv.y; acc.z += v * xv.z; acc.w += v * xv.w;
    }

    #pragma unroll
    for (int off = 16; off < 64; off <<= 1) {
        acc.x += __shfl_xor(acc.x, off);
        acc.y += __shfl_xor(acc.y, off);
        acc.z += __shfl_xor(acc.z, off);
        acc.w += __shfl_xor(acc.w, off);
    }
    if (sub == 0)
        *reinterpret_cast<float4*>(out + (size_t)r * FDIM + l * 4) = acc;
}

// ============ GEMM + bias + L2 normalize (verified) ============
__global__ __launch_bounds__(256) void gemm_norm(
    float* __restrict__ io, const float* __restrict__ W,
    const float* __restrict__ bias)
{
    __shared__ float4 Wl[64][16];
    __shared__ float4 bl[16];
    __shared__ float  s[4][4][68];

    const int t = threadIdx.x;
    for (int i = t; i < 64 * 16; i += 256)
        ((float4*)Wl)[i] = ((const float4*)W)[i];
    if (t < 16) bl[t] = ((const float4*)bias)[t];

    const int wid  = t >> 6;
    const int lane = t & 63;
    const int sub  = lane >> 4;
    const int l    = lane & 15;
    const long base = (long)blockIdx.x * 16 + wid * 4;

    float4 sv = *reinterpret_cast<const float4*>(io + base * FDIM + lane * 4);
    *reinterpret_cast<float4*>(&s[wid][lane >> 4][(lane & 15) * 4]) = sv;
    __syncthreads();

    float4 acc = {0.f, 0.f, 0.f, 0.f};
    const float* srow = s[wid][sub];
    #pragma unroll
    for (int k = 0; k < FDIM; ++k) {
        const float a = srow[k];
        const float4 w = Wl[k][l];
        acc.x += a * w.x; acc.y += a * w.y; acc.z += a * w.z; acc.w += a * w.w;
    }
    const float4 b = bl[l];
    acc.x += b.x; acc.y += b.y; acc.z += b.z; acc.w += b.w;

    float p = acc.x*acc.x + acc.y*acc.y + acc.z*acc.z + acc.w*acc.w;
    #pragma unroll
    for (int off = 1; off < 16; off <<= 1)
        p += __shfl_xor(p, off);
    const float inv = 1.0f / sqrtf(p);
    acc.x *= inv; acc.y *= inv; acc.z *= inv; acc.w *= inv;

    *reinterpret_cast<float4*>(io + (base + sub) * FDIM + l * 4) = acc;
}

extern "C" void kernel_launch(void* const* d_in, const int* in_sizes, int n_in,
                              void* d_out, int out_size, void* d_ws, size_t ws_size,
                              hipStream_t stream) {
    const float* x    = (const float*)d_in[0];
    const int*   erow = (const int*)d_in[1];
    const int*   ecol = (const int*)d_in[2];
    const float* eval = (const float*)d_in[3];
    const float* W    = (const float*)d_in[4];
    const float* bias = (const float*)d_in[5];
    float* out = (float*)d_out;
    const int n_edges = in_sizes[1];

    const int nblk = (n_edges + EDGES_PER_BLK - 1) / EDGES_PER_BLK;   // 196
    const size_t need = (size_t)WS_CV_OFF + (size_t)n_edges * sizeof(int2);
    const bool cnts_fit =
        (size_t)NBUCK * nblk * sizeof(int) <= WS_BBASE_OFF && nblk <= 256;

    if (ws_size >= need && cnts_fit) {
        int*  cnts   = (int*)d_ws;                              // dies after bin_pass2
        int*  endoff = (int*)d_ws;                              // born in sort_bucket
        int*  bbase  = (int*)((char*)d_ws + WS_BBASE_OFF);
        int*  btot   = (int*)((char*)d_ws + WS_BTOT_OFF);
        int2* cvbin  = (int2*)((char*)d_ws + WS_CV_OFF);

        count_blocks<<<nblk, 256, 0, stream>>>(erow, cnts, n_edges, nblk);
        scan_within_bucket<<<NBUCK, 256, 0, stream>>>(cnts, btot, nblk);
        scan_btot<<<1, 1024, 0, stream>>>(btot, bbase, n_edges);
        bin_pass2<<<nblk, 256, 0, stream>>>(erow, ecol, eval, cnts, bbase, cvbin,
                                            n_edges, nblk);
        sort_bucket<<<NBUCK, 256, 0, stream>>>(bbase, cvbin, endoff);
        spmm_csr<<<(N_NODES + 3) / 4, 256, 0, stream>>>(x, endoff, cvbin, out);
    } else {
        hipMemsetAsync(out, 0, (size_t)N_NODES * FDIM * sizeof(float), stream);
        long threads = (long)n_edges * 16;
        spmm_atomic<<<(int)((threads + 255) / 256), 256, 0, stream>>>(
            x, erow, ecol, eval, out, n_edges);
    }

    gemm_norm<<<N_NODES / 16, 256, 0, stream>>>(out, W, bias);
}

// Round 11
// 137.635 us; speedup vs baseline: 3.1789x; 1.0172x over previous
//
#include <hip/hip_runtime.h>

#define N_NODES 100000
#define FDIM 64
#define BROWS 128                               // rows per bucket
#define NBUCK ((N_NODES + BROWS - 1) / BROWS)   // 782
#define EDGES_PER_BLK 8192
#define BCAP 3072                               // LDS sort capacity (mean 2046, sd 45)

// ---------------- ws layout ----------------
// cnts   : off 0       NBUCK*nblk ints (within-bucket exclusive prefixes); dead after bin
// endoff : off 0       N_NODES ints (CSR row-end offsets; born in sort_bucket after cnts dies)
// bbase  : off 656 KB  NBUCK+1 ints (bucket bases + sentinel)
// btot   : off 672 KB  NBUCK ints (bucket totals)
// cvbin  : off 1 MB    n_edges int2 {col | rowlo<<20, float_bits(val)}
// xh     : off 14 MB   N_NODES*FDIM bf16 (only if ws_size permits)
#define WS_BBASE_OFF (656u * 1024u)
#define WS_BTOT_OFF  (672u * 1024u)
#define WS_CV_OFF    (1024u * 1024u)
#define WS_XH_OFF    (14u * 1024u * 1024u)

// ============ fallback (round-4 verified): fp32 HW atomics ============
__global__ __launch_bounds__(256) void spmm_atomic(
    const float* __restrict__ x, const int* __restrict__ erow,
    const int* __restrict__ ecol, const float* __restrict__ eval,
    float* __restrict__ out, int n_edges)
{
    int tid = blockIdx.x * 256 + threadIdx.x;
    int e = tid >> 4, l = tid & 15;
    if (e >= n_edges) return;
    int row = erow[e], col = ecol[e];
    float v = eval[e];
    const float4 xv = *reinterpret_cast<const float4*>(x + (size_t)col * FDIM + l * 4);
    float* dst = out + (size_t)row * FDIM + l * 4;
    unsafeAtomicAdd(dst + 0, v * xv.x);
    unsafeAtomicAdd(dst + 1, v * xv.y);
    unsafeAtomicAdd(dst + 2, v * xv.z);
    unsafeAtomicAdd(dst + 3, v * xv.w);
}

// ============ x -> bf16 (RNE) ============
__global__ __launch_bounds__(256) void convert_x(
    const float* __restrict__ x, unsigned short* __restrict__ xh)
{
    const int i = (blockIdx.x * 256 + threadIdx.x) * 8;   // 8 floats/thread
    const float4 a = *reinterpret_cast<const float4*>(x + i);
    const float4 b = *reinterpret_cast<const float4*>(x + i + 4);
    ushort4 ha, hb;
    #define BF16RNE(f) ((unsigned short)(((__float_as_uint(f) + 0x7FFFu + ((__float_as_uint(f) >> 16) & 1u)) >> 16)))
    ha.x = BF16RNE(a.x); ha.y = BF16RNE(a.y); ha.z = BF16RNE(a.z); ha.w = BF16RNE(a.w);
    hb.x = BF16RNE(b.x); hb.y = BF16RNE(b.y); hb.z = BF16RNE(b.z); hb.w = BF16RNE(b.w);
    #undef BF16RNE
    *reinterpret_cast<ushort4*>(xh + i)     = ha;
    *reinterpret_cast<ushort4*>(xh + i + 4) = hb;
}

// ============ per-(bucket,block) counts: LDS hist, plain writes (round-8 verified) ============
__global__ __launch_bounds__(256) void count_blocks(
    const int* __restrict__ erow, int* __restrict__ cnts,
    int n_edges, int nblk)
{
    __shared__ int cnt[NBUCK];
    const int blk = blockIdx.x, t = threadIdx.x;
    for (int i = t; i < NBUCK; i += 256) cnt[i] = 0;
    __syncthreads();
    const int beg = blk * EDGES_PER_BLK;
    const int end = min(beg + EDGES_PER_BLK, n_edges);
    for (int i = beg + t; i < end; i += 256)
        atomicAdd(&cnt[erow[i] >> 7], 1);
    __syncthreads();
    for (int b = t; b < NBUCK; b += 256)
        cnts[b * nblk + blk] = cnt[b];
}

// ============ within-bucket exclusive scan (782 blocks; round-9 verified) ============
__global__ __launch_bounds__(256) void scan_within_bucket(
    int* __restrict__ cnts, int* __restrict__ btot, int nblk)
{
    __shared__ int ssum[256];
    const int b = blockIdx.x, t = threadIdx.x;
    const int c = (t < nblk) ? cnts[b * nblk + t] : 0;
    ssum[t] = c;
    __syncthreads();
    for (int off = 1; off < 256; off <<= 1) {
        int v = (t >= off) ? ssum[t - off] : 0;
        __syncthreads();
        ssum[t] += v;
        __syncthreads();
    }
    if (t < nblk) cnts[b * nblk + t] = ssum[t] - c;   // exclusive
    if (t == 255) btot[b] = ssum[255];
}

// ============ scan of bucket totals -> bbase (round-9 verified) ============
__global__ __launch_bounds__(1024) void scan_btot(
    const int* __restrict__ btot, int* __restrict__ bbase, int n_edges)
{
    __shared__ int ssum[1024];
    const int t = threadIdx.x;
    const int v0 = (t < NBUCK) ? btot[t] : 0;
    ssum[t] = v0;
    __syncthreads();
    for (int off = 1; off < 1024; off <<= 1) {
        int v = (t >= off) ? ssum[t - off] : 0;
        __syncthreads();
        ssum[t] += v;
        __syncthreads();
    }
    if (t < NBUCK) bbase[t] = ssum[t] - v0;   // exclusive
    if (t == 0) bbase[NBUCK] = n_edges;       // sentinel
}

// ============ bin via block-private segments (LDS cursors; round-9 verified) ============
__global__ __launch_bounds__(256) void bin_pass2(
    const int* __restrict__ erow, const int* __restrict__ ecol,
    const float* __restrict__ eval, const int* __restrict__ cnts,
    const int* __restrict__ bbase, int2* __restrict__ cvbin,
    int n_edges, int nblk)
{
    __shared__ int cur[NBUCK];
    const int blk = blockIdx.x, t = threadIdx.x;
    for (int b = t; b < NBUCK; b += 256)
        cur[b] = bbase[b] + cnts[b * nblk + blk];
    __syncthreads();
    const int beg = blk * EDGES_PER_BLK;
    const int end = min(beg + EDGES_PER_BLK, n_edges);
    for (int i = beg + t; i < end; i += 256) {
        int r = erow[i];
        int b = r >> 7;
        int pos = atomicAdd(&cur[b], 1);            // LDS atomic
        cvbin[pos] = make_int2(ecol[i] | ((r & 127) << 20), __float_as_int(eval[i]));
    }
}

// ============ per-bucket in-place counting sort (round-7/8/9 verified) ============
__global__ __launch_bounds__(256) void sort_bucket(
    const int* __restrict__ bbase, int2* __restrict__ cvbin,
    int* __restrict__ endoff)
{
    __shared__ int2 se[BCAP];        // 24 KB
    __shared__ int  hcnt[BROWS];
    __shared__ int  tmp[BROWS];
    __shared__ int  hoff[BROWS];
    const int b = blockIdx.x, t = threadIdx.x;
    const int beg = bbase[b];
    const int end = bbase[b + 1];
    const int n = end - beg;         // ~2046 +- 45 for this input; BCAP=3072

    for (int i = t; i < n; i += 256) se[i] = cvbin[beg + i];
    if (t < BROWS) hcnt[t] = 0;
    __syncthreads();

    for (int i = t; i < n; i += 256) atomicAdd(&hcnt[se[i].x >> 20], 1);
    __syncthreads();

    if (t < BROWS) tmp[t] = hcnt[t];
    __syncthreads();
    for (int off = 1; off < BROWS; off <<= 1) {
        int val = (t < BROWS && t >= off) ? tmp[t - off] : 0;
        __syncthreads();
        if (t < BROWS) tmp[t] += val;
        __syncthreads();
    }
    if (t < BROWS) hoff[t] = tmp[t] - hcnt[t];
    __syncthreads();

    for (int i = t; i < n; i += 256) {
        int2 e = se[i];
        int pos = atomicAdd(&hoff[e.x >> 20], 1);
        cvbin[beg + pos] = e;
    }
    __syncthreads();

    if (t < BROWS) {
        int row = b * BROWS + t;
        if (row < N_NODES) endoff[row] = beg + hoff[t];
    }
}

// ============ SpMM over CSR, fp32 x (round-10 verified; ws-small path) ============
__global__ __launch_bounds__(256) void spmm_csr(
    const float* __restrict__ x, const int* __restrict__ endoff,
    const int2* __restrict__ cv, float* __restrict__ out)
{
    const int wave = (blockIdx.x * 256 + threadIdx.x) >> 6;
    if (wave >= N_NODES) return;
    const int lane = threadIdx.x & 63;
    const int sub = lane >> 4, l = lane & 15;
    const int r = wave;
    const int beg = (r == 0) ? 0 : endoff[r - 1];
    const int end = endoff[r];

    float4 acc = {0.f, 0.f, 0.f, 0.f};
    int it = beg + sub;
    for (; it + 12 < end; it += 16) {
        const int2 ea = cv[it];
        const int2 eb = cv[it + 4];
        const int2 ec = cv[it + 8];
        const int2 ed = cv[it + 12];
        const float4 xa = *reinterpret_cast<const float4*>(x + (size_t)(ea.x & 0xFFFFF) * FDIM + l * 4);
        const float4 xb = *reinterpret_cast<const float4*>(x + (size_t)(eb.x & 0xFFFFF) * FDIM + l * 4);
        const float4 xc = *reinterpret_cast<const float4*>(x + (size_t)(ec.x & 0xFFFFF) * FDIM + l * 4);
        const float4 xd = *reinterpret_cast<const float4*>(x + (size_t)(ed.x & 0xFFFFF) * FDIM + l * 4);
        const float va = __int_as_float(ea.y);
        const float vb = __int_as_float(eb.y);
        const float vc = __int_as_float(ec.y);
        const float vd = __int_as_float(ed.y);
        acc.x += va * xa.x; acc.y += va * xa.y; acc.z += va * xa.z; acc.w += va * xa.w;
        acc.x += vb * xb.x; acc.y += vb * xb.y; acc.z += vb * xb.z; acc.w += vb * xb.w;
        acc.x += vc * xc.x; acc.y += vc * xc.y; acc.z += vc * xc.z; acc.w += vc * xc.w;
        acc.x += vd * xd.x; acc.y += vd * xd.y; acc.z += vd * xd.z; acc.w += vd * xd.w;
    }
    for (; it < end; it += 4) {
        const int2 e = cv[it];
        const float v = __int_as_float(e.y);
        const float4 xv = *reinterpret_cast<const float4*>(x + (size_t)(e.x & 0xFFFFF) * FDIM + l * 4);
        acc.x += v * xv.x; acc.y += v * xv.y; acc.z += v * xv.z; acc.w += v * xv.w;
    }
    #pragma unroll
    for (int off = 16; off < 64; off <<= 1) {
        acc.x += __shfl_xor(acc.x, off);
        acc.y += __shfl_xor(acc.y, off);
        acc.z += __shfl_xor(acc.z, off);
        acc.w += __shfl_xor(acc.w, off);
    }
    if (sub == 0)
        *reinterpret_cast<float4*>(out + (size_t)r * FDIM + l * 4) = acc;
}

// ============ SpMM over CSR, bf16 x: half the gather bytes ============
__device__ __forceinline__ float bf2f(unsigned short h) {
    return __uint_as_float((unsigned int)h << 16);
}

__global__ __launch_bounds__(256) void spmm_csr_h(
    const unsigned short* __restrict__ xh, const int* __restrict__ endoff,
    const int2* __restrict__ cv, float* __restrict__ out)
{
    const int wave = (blockIdx.x * 256 + threadIdx.x) >> 6;
    if (wave >= N_NODES) return;
    const int lane = threadIdx.x & 63;
    const int sub = lane >> 4, l = lane & 15;
    const int r = wave;
    const int beg = (r == 0) ? 0 : endoff[r - 1];
    const int end = endoff[r];

    float4 acc = {0.f, 0.f, 0.f, 0.f};
    int it = beg + sub;
    for (; it + 12 < end; it += 16) {
        const int2 ea = cv[it];
        const int2 eb = cv[it + 4];
        const int2 ec = cv[it + 8];
        const int2 ed = cv[it + 12];
        const ushort4 xa = *reinterpret_cast<const ushort4*>(xh + (size_t)(ea.x & 0xFFFFF) * FDIM + l * 4);
        const ushort4 xb = *reinterpret_cast<const ushort4*>(xh + (size_t)(eb.x & 0xFFFFF) * FDIM + l * 4);
        const ushort4 xc = *reinterpret_cast<const ushort4*>(xh + (size_t)(ec.x & 0xFFFFF) * FDIM + l * 4);
        const ushort4 xd = *reinterpret_cast<const ushort4*>(xh + (size_t)(ed.x & 0xFFFFF) * FDIM + l * 4);
        const float va = __int_as_float(ea.y);
        const float vb = __int_as_float(eb.y);
        const float vc = __int_as_float(ec.y);
        const float vd = __int_as_float(ed.y);
        acc.x += va * bf2f(xa.x); acc.y += va * bf2f(xa.y); acc.z += va * bf2f(xa.z); acc.w += va * bf2f(xa.w);
        acc.x += vb * bf2f(xb.x); acc.y += vb * bf2f(xb.y); acc.z += vb * bf2f(xb.z); acc.w += vb * bf2f(xb.w);
        acc.x += vc * bf2f(xc.x); acc.y += vc * bf2f(xc.y); acc.z += vc * bf2f(xc.z); acc.w += vc * bf2f(xc.w);
        acc.x += vd * bf2f(xd.x); acc.y += vd * bf2f(xd.y); acc.z += vd * bf2f(xd.z); acc.w += vd * bf2f(xd.w);
    }
    for (; it < end; it += 4) {
        const int2 e = cv[it];
        const float v = __int_as_float(e.y);
        const ushort4 xv = *reinterpret_cast<const ushort4*>(xh + (size_t)(e.x & 0xFFFFF) * FDIM + l * 4);
        acc.x += v * bf2f(xv.x); acc.y += v * bf2f(xv.y); acc.z += v * bf2f(xv.z); acc.w += v * bf2f(xv.w);
    }
    #pragma unroll
    for (int off = 16; off < 64; off <<= 1) {
        acc.x += __shfl_xor(acc.x, off);
        acc.y += __shfl_xor(acc.y, off);
        acc.z += __shfl_xor(acc.z, off);
        acc.w += __shfl_xor(acc.w, off);
    }
    if (sub == 0)
        *reinterpret_cast<float4*>(out + (size_t)r * FDIM + l * 4) = acc;
}

// ============ GEMM + bias + L2 normalize (verified) ============
__global__ __launch_bounds__(256) void gemm_norm(
    float* __restrict__ io, const float* __restrict__ W,
    const float* __restrict__ bias)
{
    __shared__ float4 Wl[64][16];
    __shared__ float4 bl[16];
    __shared__ float  s[4][4][68];

    const int t = threadIdx.x;
    for (int i = t; i < 64 * 16; i += 256)
        ((float4*)Wl)[i] = ((const float4*)W)[i];
    if (t < 16) bl[t] = ((const float4*)bias)[t];

    const int wid  = t >> 6;
    const int lane = t & 63;
    const int sub  = lane >> 4;
    const int l    = lane & 15;
    const long base = (long)blockIdx.x * 16 + wid * 4;

    float4 sv = *reinterpret_cast<const float4*>(io + base * FDIM + lane * 4);
    *reinterpret_cast<float4*>(&s[wid][lane >> 4][(lane & 15) * 4]) = sv;
    __syncthreads();

    float4 acc = {0.f, 0.f, 0.f, 0.f};
    const float* srow = s[wid][sub];
    #pragma unroll
    for (int k = 0; k < FDIM; ++k) {
        const float a = srow[k];
        const float4 w = Wl[k][l];
        acc.x += a * w.x; acc.y += a * w.y; acc.z += a * w.z; acc.w += a * w.w;
    }
    const float4 b = bl[l];
    acc.x += b.x; acc.y += b.y; acc.z += b.z; acc.w += b.w;

    float p = acc.x*acc.x + acc.y*acc.y + acc.z*acc.z + acc.w*acc.w;
    #pragma unroll
    for (int off = 1; off < 16; off <<= 1)
        p += __shfl_xor(p, off);
    const float inv = 1.0f / sqrtf(p);
    acc.x *= inv; acc.y *= inv; acc.z *= inv; acc.w *= inv;

    *reinterpret_cast<float4*>(io + (base + sub) * FDIM + l * 4) = acc;
}

extern "C" void kernel_launch(void* const* d_in, const int* in_sizes, int n_in,
                              void* d_out, int out_size, void* d_ws, size_t ws_size,
                              hipStream_t stream) {
    const float* x    = (const float*)d_in[0];
    const int*   erow = (const int*)d_in[1];
    const int*   ecol = (const int*)d_in[2];
    const float* eval = (const float*)d_in[3];
    const float* W    = (const float*)d_in[4];
    const float* bias = (const float*)d_in[5];
    float* out = (float*)d_out;
    const int n_edges = in_sizes[1];

    const int nblk = (n_edges + EDGES_PER_BLK - 1) / EDGES_PER_BLK;   // 196
    const size_t need = (size_t)WS_CV_OFF + (size_t)n_edges * sizeof(int2);
    const size_t need_bf16 = (size_t)WS_XH_OFF + (size_t)N_NODES * FDIM * sizeof(short);
    const bool cnts_fit =
        (size_t)NBUCK * nblk * sizeof(int) <= WS_BBASE_OFF && nblk <= 256;

    if (ws_size >= need && cnts_fit) {
        int*  cnts   = (int*)d_ws;                              // dies after bin_pass2
        int*  endoff = (int*)d_ws;                              // born in sort_bucket
        int*  bbase  = (int*)((char*)d_ws + WS_BBASE_OFF);
        int*  btot   = (int*)((char*)d_ws + WS_BTOT_OFF);
        int2* cvbin  = (int2*)((char*)d_ws + WS_CV_OFF);
        unsigned short* xh = (unsigned short*)((char*)d_ws + WS_XH_OFF);
        const bool use_bf16 = (ws_size >= need_bf16);

        if (use_bf16)
            convert_x<<<(N_NODES * FDIM) / (256 * 8), 256, 0, stream>>>(x, xh);
        count_blocks<<<nblk, 256, 0, stream>>>(erow, cnts, n_edges, nblk);
        scan_within_bucket<<<NBUCK, 256, 0, stream>>>(cnts, btot, nblk);
        scan_btot<<<1, 1024, 0, stream>>>(btot, bbase, n_edges);
        bin_pass2<<<nblk, 256, 0, stream>>>(erow, ecol, eval, cnts, bbase, cvbin,
                                            n_edges, nblk);
        sort_bucket<<<NBUCK, 256, 0, stream>>>(bbase, cvbin, endoff);
        if (use_bf16)
            spmm_csr_h<<<(N_NODES + 3) / 4, 256, 0, stream>>>(xh, endoff, cvbin, out);
        else
            spmm_csr<<<(N_NODES + 3) / 4, 256, 0, stream>>>(x, endoff, cvbin, out);
    } else {
        hipMemsetAsync(out, 0, (size_t)N_NODES * FDIM * sizeof(float), stream);
        long threads = (long)n_edges * 16;
        spmm_atomic<<<(int)((threads + 255) / 256), 256, 0, stream>>>(
            x, erow, ecol, eval, out, n_edges);
    }

    gemm_norm<<<N_NODES / 16, 256, 0, stream>>>(out, W, bias);
}

// Round 12
// 121.732 us; speedup vs baseline: 3.5941x; 1.1306x over previous
//
#include <hip/hip_runtime.h>

#define N_NODES 100000
#define FDIM 64
#define BROWS 128                               // rows per bucket
#define NBUCK ((N_NODES + BROWS - 1) / BROWS)   // 782
#define EDGES_PER_BLK 8192
#define BCAP 3072                               // LDS sort capacity (mean 2046, sd 45)

// ---------------- ws layout ----------------
// cnts   : off 0       NBUCK*nblk ints (within-bucket exclusive prefixes); dead after bin
// endoff : off 0       N_NODES ints (CSR row-end offsets; born in sort_bucket after cnts dies)
// bbase  : off 656 KB  NBUCK+1 ints (bucket bases + sentinel)
// btot   : off 672 KB  NBUCK ints (bucket totals)
// cvbin  : off 1 MB    n_edges int2 {col | rowlo<<20, float_bits(val)}
// xh     : off 14 MB   N_NODES*FDIM bf16 (only if ws_size permits)
#define WS_BBASE_OFF (656u * 1024u)
#define WS_BTOT_OFF  (672u * 1024u)
#define WS_CV_OFF    (1024u * 1024u)
#define WS_XH_OFF    (14u * 1024u * 1024u)

// ============ fallback (round-4 verified): fp32 HW atomics ============
__global__ __launch_bounds__(256) void spmm_atomic(
    const float* __restrict__ x, const int* __restrict__ erow,
    const int* __restrict__ ecol, const float* __restrict__ eval,
    float* __restrict__ out, int n_edges)
{
    int tid = blockIdx.x * 256 + threadIdx.x;
    int e = tid >> 4, l = tid & 15;
    if (e >= n_edges) return;
    int row = erow[e], col = ecol[e];
    float v = eval[e];
    const float4 xv = *reinterpret_cast<const float4*>(x + (size_t)col * FDIM + l * 4);
    float* dst = out + (size_t)row * FDIM + l * 4;
    unsafeAtomicAdd(dst + 0, v * xv.x);
    unsafeAtomicAdd(dst + 1, v * xv.y);
    unsafeAtomicAdd(dst + 2, v * xv.z);
    unsafeAtomicAdd(dst + 3, v * xv.w);
}

// ============ x -> bf16 (RNE) ============
__global__ __launch_bounds__(256) void convert_x(
    const float* __restrict__ x, unsigned short* __restrict__ xh)
{
    const int i = (blockIdx.x * 256 + threadIdx.x) * 8;   // 8 floats/thread
    const float4 a = *reinterpret_cast<const float4*>(x + i);
    const float4 b = *reinterpret_cast<const float4*>(x + i + 4);
    ushort4 ha, hb;
    #define BF16RNE(f) ((unsigned short)(((__float_as_uint(f) + 0x7FFFu + ((__float_as_uint(f) >> 16) & 1u)) >> 16)))
    ha.x = BF16RNE(a.x); ha.y = BF16RNE(a.y); ha.z = BF16RNE(a.z); ha.w = BF16RNE(a.w);
    hb.x = BF16RNE(b.x); hb.y = BF16RNE(b.y); hb.z = BF16RNE(b.z); hb.w = BF16RNE(b.w);
    #undef BF16RNE
    *reinterpret_cast<ushort4*>(xh + i)     = ha;
    *reinterpret_cast<ushort4*>(xh + i + 4) = hb;
}

// ============ per-(bucket,block) counts: 1024 threads/chunk ============
__global__ __launch_bounds__(1024) void count_blocks(
    const int* __restrict__ erow, int* __restrict__ cnts,
    int n_edges, int nblk)
{
    __shared__ int cnt[NBUCK];
    const int blk = blockIdx.x, t = threadIdx.x;
    for (int i = t; i < NBUCK; i += 1024) cnt[i] = 0;
    __syncthreads();
    const int beg = blk * EDGES_PER_BLK;
    const int end = min(beg + EDGES_PER_BLK, n_edges);
    for (int i = beg + t; i < end; i += 1024)
        atomicAdd(&cnt[erow[i] >> 7], 1);
    __syncthreads();
    for (int b = t; b < NBUCK; b += 1024)
        cnts[b * nblk + blk] = cnt[b];
}

// ============ within-bucket exclusive scan (782 blocks; round-9 verified) ============
__global__ __launch_bounds__(256) void scan_within_bucket(
    int* __restrict__ cnts, int* __restrict__ btot, int nblk)
{
    __shared__ int ssum[256];
    const int b = blockIdx.x, t = threadIdx.x;
    const int c = (t < nblk) ? cnts[b * nblk + t] : 0;
    ssum[t] = c;
    __syncthreads();
    for (int off = 1; off < 256; off <<= 1) {
        int v = (t >= off) ? ssum[t - off] : 0;
        __syncthreads();
        ssum[t] += v;
        __syncthreads();
    }
    if (t < nblk) cnts[b * nblk + t] = ssum[t] - c;   // exclusive
    if (t == 255) btot[b] = ssum[255];
}

// ============ scan of bucket totals -> bbase (round-9 verified) ============
__global__ __launch_bounds__(1024) void scan_btot(
    const int* __restrict__ btot, int* __restrict__ bbase, int n_edges)
{
    __shared__ int ssum[1024];
    const int t = threadIdx.x;
    const int v0 = (t < NBUCK) ? btot[t] : 0;
    ssum[t] = v0;
    __syncthreads();
    for (int off = 1; off < 1024; off <<= 1) {
        int v = (t >= off) ? ssum[t - off] : 0;
        __syncthreads();
        ssum[t] += v;
        __syncthreads();
    }
    if (t < NBUCK) bbase[t] = ssum[t] - v0;   // exclusive
    if (t == 0) bbase[NBUCK] = n_edges;       // sentinel
}

// ============ bin via block-private segments: 1024 threads/chunk ============
__global__ __launch_bounds__(1024) void bin_pass2(
    const int* __restrict__ erow, const int* __restrict__ ecol,
    const float* __restrict__ eval, const int* __restrict__ cnts,
    const int* __restrict__ bbase, int2* __restrict__ cvbin,
    int n_edges, int nblk)
{
    __shared__ int cur[NBUCK];
    const int blk = blockIdx.x, t = threadIdx.x;
    for (int b = t; b < NBUCK; b += 1024)
        cur[b] = bbase[b] + cnts[b * nblk + blk];
    __syncthreads();
    const int beg = blk * EDGES_PER_BLK;
    const int end = min(beg + EDGES_PER_BLK, n_edges);
    for (int i = beg + t; i < end; i += 1024) {
        int r = erow[i];
        int b = r >> 7;
        int pos = atomicAdd(&cur[b], 1);            // LDS atomic
        cvbin[pos] = make_int2(ecol[i] | ((r & 127) << 20), __float_as_int(eval[i]));
    }
}

// ============ per-bucket in-place counting sort (round-7/8/9 verified) ============
__global__ __launch_bounds__(256) void sort_bucket(
    const int* __restrict__ bbase, int2* __restrict__ cvbin,
    int* __restrict__ endoff)
{
    __shared__ int2 se[BCAP];        // 24 KB
    __shared__ int  hcnt[BROWS];
    __shared__ int  tmp[BROWS];
    __shared__ int  hoff[BROWS];
    const int b = blockIdx.x, t = threadIdx.x;
    const int beg = bbase[b];
    const int end = bbase[b + 1];
    const int n = end - beg;         // ~2046 +- 45 for this input; BCAP=3072

    for (int i = t; i < n; i += 256) se[i] = cvbin[beg + i];
    if (t < BROWS) hcnt[t] = 0;
    __syncthreads();

    for (int i = t; i < n; i += 256) atomicAdd(&hcnt[se[i].x >> 20], 1);
    __syncthreads();

    if (t < BROWS) tmp[t] = hcnt[t];
    __syncthreads();
    for (int off = 1; off < BROWS; off <<= 1) {
        int val = (t < BROWS && t >= off) ? tmp[t - off] : 0;
        __syncthreads();
        if (t < BROWS) tmp[t] += val;
        __syncthreads();
    }
    if (t < BROWS) hoff[t] = tmp[t] - hcnt[t];
    __syncthreads();

    for (int i = t; i < n; i += 256) {
        int2 e = se[i];
        int pos = atomicAdd(&hoff[e.x >> 20], 1);
        cvbin[beg + pos] = e;
    }
    __syncthreads();

    if (t < BROWS) {
        int row = b * BROWS + t;
        if (row < N_NODES) endoff[row] = beg + hoff[t];
    }
}

// ============ SpMM over CSR, fp32 x (round-10 verified; ws-small path) ============
__global__ __launch_bounds__(256) void spmm_csr(
    const float* __restrict__ x, const int* __restrict__ endoff,
    const int2* __restrict__ cv, float* __restrict__ out)
{
    const int wave = (blockIdx.x * 256 + threadIdx.x) >> 6;
    if (wave >= N_NODES) return;
    const int lane = threadIdx.x & 63;
    const int sub = lane >> 4, l = lane & 15;
    const int r = wave;
    const int beg = (r == 0) ? 0 : endoff[r - 1];
    const int end = endoff[r];

    float4 acc = {0.f, 0.f, 0.f, 0.f};
    int it = beg + sub;
    for (; it + 12 < end; it += 16) {
        const int2 ea = cv[it];
        const int2 eb = cv[it + 4];
        const int2 ec = cv[it + 8];
        const int2 ed = cv[it + 12];
        const float4 xa = *reinterpret_cast<const float4*>(x + (size_t)(ea.x & 0xFFFFF) * FDIM + l * 4);
        const float4 xb = *reinterpret_cast<const float4*>(x + (size_t)(eb.x & 0xFFFFF) * FDIM + l * 4);
        const float4 xc = *reinterpret_cast<const float4*>(x + (size_t)(ec.x & 0xFFFFF) * FDIM + l * 4);
        const float4 xd = *reinterpret_cast<const float4*>(x + (size_t)(ed.x & 0xFFFFF) * FDIM + l * 4);
        const float va = __int_as_float(ea.y);
        const float vb = __int_as_float(eb.y);
        const float vc = __int_as_float(ec.y);
        const float vd = __int_as_float(ed.y);
        acc.x += va * xa.x; acc.y += va * xa.y; acc.z += va * xa.z; acc.w += va * xa.w;
        acc.x += vb * xb.x; acc.y += vb * xb.y; acc.z += vb * xb.z; acc.w += vb * xb.w;
        acc.x += vc * xc.x; acc.y += vc * xc.y; acc.z += vc * xc.z; acc.w += vc * xc.w;
        acc.x += vd * xd.x; acc.y += vd * xd.y; acc.z += vd * xd.z; acc.w += vd * xd.w;
    }
    for (; it < end; it += 4) {
        const int2 e = cv[it];
        const float v = __int_as_float(e.y);
        const float4 xv = *reinterpret_cast<const float4*>(x + (size_t)(e.x & 0xFFFFF) * FDIM + l * 4);
        acc.x += v * xv.x; acc.y += v * xv.y; acc.z += v * xv.z; acc.w += v * xv.w;
    }
    #pragma unroll
    for (int off = 16; off < 64; off <<= 1) {
        acc.x += __shfl_xor(acc.x, off);
        acc.y += __shfl_xor(acc.y, off);
        acc.z += __shfl_xor(acc.z, off);
        acc.w += __shfl_xor(acc.w, off);
    }
    if (sub == 0)
        *reinterpret_cast<float4*>(out + (size_t)r * FDIM + l * 4) = acc;
}

// ============ SpMM over CSR, bf16 x (round-11 verified) ============
__device__ __forceinline__ float bf2f(unsigned short h) {
    return __uint_as_float((unsigned int)h << 16);
}

__global__ __launch_bounds__(256) void spmm_csr_h(
    const unsigned short* __restrict__ xh, const int* __restrict__ endoff,
    const int2* __restrict__ cv, float* __restrict__ out)
{
    const int wave = (blockIdx.x * 256 + threadIdx.x) >> 6;
    if (wave >= N_NODES) return;
    const int lane = threadIdx.x & 63;
    const int sub = lane >> 4, l = lane & 15;
    const int r = wave;
    const int beg = (r == 0) ? 0 : endoff[r - 1];
    const int end = endoff[r];

    float4 acc = {0.f, 0.f, 0.f, 0.f};
    int it = beg + sub;
    for (; it + 12 < end; it += 16) {
        const int2 ea = cv[it];
        const int2 eb = cv[it + 4];
        const int2 ec = cv[it + 8];
        const int2 ed = cv[it + 12];
        const ushort4 xa = *reinterpret_cast<const ushort4*>(xh + (size_t)(ea.x & 0xFFFFF) * FDIM + l * 4);
        const ushort4 xb = *reinterpret_cast<const ushort4*>(xh + (size_t)(eb.x & 0xFFFFF) * FDIM + l * 4);
        const ushort4 xc = *reinterpret_cast<const ushort4*>(xh + (size_t)(ec.x & 0xFFFFF) * FDIM + l * 4);
        const ushort4 xd = *reinterpret_cast<const ushort4*>(xh + (size_t)(ed.x & 0xFFFFF) * FDIM + l * 4);
        const float va = __int_as_float(ea.y);
        const float vb = __int_as_float(eb.y);
        const float vc = __int_as_float(ec.y);
        const float vd = __int_as_float(ed.y);
        acc.x += va * bf2f(xa.x); acc.y += va * bf2f(xa.y); acc.z += va * bf2f(xa.z); acc.w += va * bf2f(xa.w);
        acc.x += vb * bf2f(xb.x); acc.y += vb * bf2f(xb.y); acc.z += vb * bf2f(xb.z); acc.w += vb * bf2f(xb.w);
        acc.x += vc * bf2f(xc.x); acc.y += vc * bf2f(xc.y); acc.z += vc * bf2f(xc.z); acc.w += vc * bf2f(xc.w);
        acc.x += vd * bf2f(xd.x); acc.y += vd * bf2f(xd.y); acc.z += vd * bf2f(xd.z); acc.w += vd * bf2f(xd.w);
    }
    for (; it < end; it += 4) {
        const int2 e = cv[it];
        const float v = __int_as_float(e.y);
        const ushort4 xv = *reinterpret_cast<const ushort4*>(xh + (size_t)(e.x & 0xFFFFF) * FDIM + l * 4);
        acc.x += v * bf2f(xv.x); acc.y += v * bf2f(xv.y); acc.z += v * bf2f(xv.z); acc.w += v * bf2f(xv.w);
    }
    #pragma unroll
    for (int off = 16; off < 64; off <<= 1) {
        acc.x += __shfl_xor(acc.x, off);
        acc.y += __shfl_xor(acc.y, off);
        acc.z += __shfl_xor(acc.z, off);
        acc.w += __shfl_xor(acc.w, off);
    }
    if (sub == 0)
        *reinterpret_cast<float4*>(out + (size_t)r * FDIM + l * 4) = acc;
}

// ============ GEMM + bias + L2 normalize (verified) ============
__global__ __launch_bounds__(256) void gemm_norm(
    float* __restrict__ io, const float* __restrict__ W,
    const float* __restrict__ bias)
{
    __shared__ float4 Wl[64][16];
    __shared__ float4 bl[16];
    __shared__ float  s[4][4][68];

    const int t = threadIdx.x;
    for (int i = t; i < 64 * 16; i += 256)
        ((float4*)Wl)[i] = ((const float4*)W)[i];
    if (t < 16) bl[t] = ((const float4*)bias)[t];

    const int wid  = t >> 6;
    const int lane = t & 63;
    const int sub  = lane >> 4;
    const int l    = lane & 15;
    const long base = (long)blockIdx.x * 16 + wid * 4;

    float4 sv = *reinterpret_cast<const float4*>(io + base * FDIM + lane * 4);
    *reinterpret_cast<float4*>(&s[wid][lane >> 4][(lane & 15) * 4]) = sv;
    __syncthreads();

    float4 acc = {0.f, 0.f, 0.f, 0.f};
    const float* srow = s[wid][sub];
    #pragma unroll
    for (int k = 0; k < FDIM; ++k) {
        const float a = srow[k];
        const float4 w = Wl[k][l];
        acc.x += a * w.x; acc.y += a * w.y; acc.z += a * w.z; acc.w += a * w.w;
    }
    const float4 b = bl[l];
    acc.x += b.x; acc.y += b.y; acc.z += b.z; acc.w += b.w;

    float p = acc.x*acc.x + acc.y*acc.y + acc.z*acc.z + acc.w*acc.w;
    #pragma unroll
    for (int off = 1; off < 16; off <<= 1)
        p += __shfl_xor(p, off);
    const float inv = 1.0f / sqrtf(p);
    acc.x *= inv; acc.y *= inv; acc.z *= inv; acc.w *= inv;

    *reinterpret_cast<float4*>(io + (base + sub) * FDIM + l * 4) = acc;
}

extern "C" void kernel_launch(void* const* d_in, const int* in_sizes, int n_in,
                              void* d_out, int out_size, void* d_ws, size_t ws_size,
                              hipStream_t stream) {
    const float* x    = (const float*)d_in[0];
    const int*   erow = (const int*)d_in[1];
    const int*   ecol = (const int*)d_in[2];
    const float* eval = (const float*)d_in[3];
    const float* W    = (const float*)d_in[4];
    const float* bias = (const float*)d_in[5];
    float* out = (float*)d_out;
    const int n_edges = in_sizes[1];

    const int nblk = (n_edges + EDGES_PER_BLK - 1) / EDGES_PER_BLK;   // 196
    const size_t need = (size_t)WS_CV_OFF + (size_t)n_edges * sizeof(int2);
    const size_t need_bf16 = (size_t)WS_XH_OFF + (size_t)N_NODES * FDIM * sizeof(short);
    const bool cnts_fit =
        (size_t)NBUCK * nblk * sizeof(int) <= WS_BBASE_OFF && nblk <= 256;

    if (ws_size >= need && cnts_fit) {
        int*  cnts   = (int*)d_ws;                              // dies after bin_pass2
        int*  endoff = (int*)d_ws;                              // born in sort_bucket
        int*  bbase  = (int*)((char*)d_ws + WS_BBASE_OFF);
        int*  btot   = (int*)((char*)d_ws + WS_BTOT_OFF);
        int2* cvbin  = (int2*)((char*)d_ws + WS_CV_OFF);
        unsigned short* xh = (unsigned short*)((char*)d_ws + WS_XH_OFF);
        const bool use_bf16 = (ws_size >= need_bf16);

        if (use_bf16)
            convert_x<<<(N_NODES * FDIM) / (256 * 8), 256, 0, stream>>>(x, xh);
        count_blocks<<<nblk, 1024, 0, stream>>>(erow, cnts, n_edges, nblk);
        scan_within_bucket<<<NBUCK, 256, 0, stream>>>(cnts, btot, nblk);
        scan_btot<<<1, 1024, 0, stream>>>(btot, bbase, n_edges);
        bin_pass2<<<nblk, 1024, 0, stream>>>(erow, ecol, eval, cnts, bbase, cvbin,
                                             n_edges, nblk);
        sort_bucket<<<NBUCK, 256, 0, stream>>>(bbase, cvbin, endoff);
        if (use_bf16)
            spmm_csr_h<<<(N_NODES + 3) / 4, 256, 0, stream>>>(xh, endoff, cvbin, out);
        else
            spmm_csr<<<(N_NODES + 3) / 4, 256, 0, stream>>>(x, endoff, cvbin, out);
    } else {
        hipMemsetAsync(out, 0, (size_t)N_NODES * FDIM * sizeof(float), stream);
        long threads = (long)n_edges * 16;
        spmm_atomic<<<(int)((threads + 255) / 256), 256, 0, stream>>>(
            x, erow, ecol, eval, out, n_edges);
    }

    gemm_norm<<<N_NODES / 16, 256, 0, stream>>>(out, W, bias);
}

// Round 13
// 111.016 us; speedup vs baseline: 3.9410x; 1.0965x over previous
//
#include <hip/hip_runtime.h>

#define N_NODES 100000
#define FDIM 64
#define BROWS 128                               // rows per bucket
#define NBUCK ((N_NODES + BROWS - 1) / BROWS)   // 782
#define EDGES_PER_BLK 8192
#define BCAP 3072                               // LDS sort capacity (mean 2046, sd 45)

// ---------------- ws layout ----------------
// cnts   : off 0       NBUCK*nblk ints (within-bucket exclusive prefixes); dead after bin
// endoff : off 0       N_NODES ints (CSR row-end offsets; born in sort_bucket after cnts dies)
// bbase  : off 656 KB  NBUCK+1 ints (bucket bases + sentinel)
// btot   : off 672 KB  NBUCK ints (bucket totals)
// cvbin  : off 1 MB    n_edges int2 {col | rowlo<<20, float_bits(val)}
// xh     : off 14 MB   N_NODES*FDIM bf16 (only if ws_size permits)
#define WS_BBASE_OFF (656u * 1024u)
#define WS_BTOT_OFF  (672u * 1024u)
#define WS_CV_OFF    (1024u * 1024u)
#define WS_XH_OFF    (14u * 1024u * 1024u)

// ============ fallback (round-4 verified): fp32 HW atomics ============
__global__ __launch_bounds__(256) void spmm_atomic(
    const float* __restrict__ x, const int* __restrict__ erow,
    const int* __restrict__ ecol, const float* __restrict__ eval,
    float* __restrict__ out, int n_edges)
{
    int tid = blockIdx.x * 256 + threadIdx.x;
    int e = tid >> 4, l = tid & 15;
    if (e >= n_edges) return;
    int row = erow[e], col = ecol[e];
    float v = eval[e];
    const float4 xv = *reinterpret_cast<const float4*>(x + (size_t)col * FDIM + l * 4);
    float* dst = out + (size_t)row * FDIM + l * 4;
    unsafeAtomicAdd(dst + 0, v * xv.x);
    unsafeAtomicAdd(dst + 1, v * xv.y);
    unsafeAtomicAdd(dst + 2, v * xv.z);
    unsafeAtomicAdd(dst + 3, v * xv.w);
}

// ============ x -> bf16 (RNE) ============
__global__ __launch_bounds__(256) void convert_x(
    const float* __restrict__ x, unsigned short* __restrict__ xh)
{
    const int i = (blockIdx.x * 256 + threadIdx.x) * 8;   // 8 floats/thread
    const float4 a = *reinterpret_cast<const float4*>(x + i);
    const float4 b = *reinterpret_cast<const float4*>(x + i + 4);
    ushort4 ha, hb;
    #define BF16RNE(f) ((unsigned short)(((__float_as_uint(f) + 0x7FFFu + ((__float_as_uint(f) >> 16) & 1u)) >> 16)))
    ha.x = BF16RNE(a.x); ha.y = BF16RNE(a.y); ha.z = BF16RNE(a.z); ha.w = BF16RNE(a.w);
    hb.x = BF16RNE(b.x); hb.y = BF16RNE(b.y); hb.z = BF16RNE(b.z); hb.w = BF16RNE(b.w);
    #undef BF16RNE
    *reinterpret_cast<ushort4*>(xh + i)     = ha;
    *reinterpret_cast<ushort4*>(xh + i + 4) = hb;
}

// ============ per-(bucket,block) counts: 1024 threads/chunk (round-12 verified) ============
__global__ __launch_bounds__(1024) void count_blocks(
    const int* __restrict__ erow, int* __restrict__ cnts,
    int n_edges, int nblk)
{
    __shared__ int cnt[NBUCK];
    const int blk = blockIdx.x, t = threadIdx.x;
    for (int i = t; i < NBUCK; i += 1024) cnt[i] = 0;
    __syncthreads();
    const int beg = blk * EDGES_PER_BLK;
    const int end = min(beg + EDGES_PER_BLK, n_edges);
    for (int i = beg + t; i < end; i += 1024)
        atomicAdd(&cnt[erow[i] >> 7], 1);
    __syncthreads();
    for (int b = t; b < NBUCK; b += 1024)
        cnts[b * nblk + blk] = cnt[b];
}

// ============ within-bucket exclusive scan (782 blocks; round-9 verified) ============
__global__ __launch_bounds__(256) void scan_within_bucket(
    int* __restrict__ cnts, int* __restrict__ btot, int nblk)
{
    __shared__ int ssum[256];
    const int b = blockIdx.x, t = threadIdx.x;
    const int c = (t < nblk) ? cnts[b * nblk + t] : 0;
    ssum[t] = c;
    __syncthreads();
    for (int off = 1; off < 256; off <<= 1) {
        int v = (t >= off) ? ssum[t - off] : 0;
        __syncthreads();
        ssum[t] += v;
        __syncthreads();
    }
    if (t < nblk) cnts[b * nblk + t] = ssum[t] - c;   // exclusive
    if (t == 255) btot[b] = ssum[255];
}

// ============ scan of bucket totals -> bbase (round-9 verified) ============
__global__ __launch_bounds__(1024) void scan_btot(
    const int* __restrict__ btot, int* __restrict__ bbase, int n_edges)
{
    __shared__ int ssum[1024];
    const int t = threadIdx.x;
    const int v0 = (t < NBUCK) ? btot[t] : 0;
    ssum[t] = v0;
    __syncthreads();
    for (int off = 1; off < 1024; off <<= 1) {
        int v = (t >= off) ? ssum[t - off] : 0;
        __syncthreads();
        ssum[t] += v;
        __syncthreads();
    }
    if (t < NBUCK) bbase[t] = ssum[t] - v0;   // exclusive
    if (t == 0) bbase[NBUCK] = n_edges;       // sentinel
}

// ============ bin via block-private segments: 1024 threads/chunk (round-12 verified) ============
__global__ __launch_bounds__(1024) void bin_pass2(
    const int* __restrict__ erow, const int* __restrict__ ecol,
    const float* __restrict__ eval, const int* __restrict__ cnts,
    const int* __restrict__ bbase, int2* __restrict__ cvbin,
    int n_edges, int nblk)
{
    __shared__ int cur[NBUCK];
    const int blk = blockIdx.x, t = threadIdx.x;
    for (int b = t; b < NBUCK; b += 1024)
        cur[b] = bbase[b] + cnts[b * nblk + blk];
    __syncthreads();
    const int beg = blk * EDGES_PER_BLK;
    const int end = min(beg + EDGES_PER_BLK, n_edges);
    for (int i = beg + t; i < end; i += 1024) {
        int r = erow[i];
        int b = r >> 7;
        int pos = atomicAdd(&cur[b], 1);            // LDS atomic
        cvbin[pos] = make_int2(ecol[i] | ((r & 127) << 20), __float_as_int(eval[i]));
    }
}

// ============ per-bucket in-place counting sort (round-7/8/9 verified) ============
__global__ __launch_bounds__(256) void sort_bucket(
    const int* __restrict__ bbase, int2* __restrict__ cvbin,
    int* __restrict__ endoff)
{
    __shared__ int2 se[BCAP];        // 24 KB
    __shared__ int  hcnt[BROWS];
    __shared__ int  tmp[BROWS];
    __shared__ int  hoff[BROWS];
    const int b = blockIdx.x, t = threadIdx.x;
    const int beg = bbase[b];
    const int end = bbase[b + 1];
    const int n = end - beg;         // ~2046 +- 45 for this input; BCAP=3072

    for (int i = t; i < n; i += 256) se[i] = cvbin[beg + i];
    if (t < BROWS) hcnt[t] = 0;
    __syncthreads();

    for (int i = t; i < n; i += 256) atomicAdd(&hcnt[se[i].x >> 20], 1);
    __syncthreads();

    if (t < BROWS) tmp[t] = hcnt[t];
    __syncthreads();
    for (int off = 1; off < BROWS; off <<= 1) {
        int val = (t < BROWS && t >= off) ? tmp[t - off] : 0;
        __syncthreads();
        if (t < BROWS) tmp[t] += val;
        __syncthreads();
    }
    if (t < BROWS) hoff[t] = tmp[t] - hcnt[t];
    __syncthreads();

    for (int i = t; i < n; i += 256) {
        int2 e = se[i];
        int pos = atomicAdd(&hoff[e.x >> 20], 1);
        cvbin[beg + pos] = e;
    }
    __syncthreads();

    if (t < BROWS) {
        int row = b * BROWS + t;
        if (row < N_NODES) endoff[row] = beg + hoff[t];
    }
}

// ============ SpMM over CSR, fp32 x (round-10 verified; ws-small path) ============
__global__ __launch_bounds__(256) void spmm_csr(
    const float* __restrict__ x, const int* __restrict__ endoff,
    const int2* __restrict__ cv, float* __restrict__ out)
{
    const int wave = (blockIdx.x * 256 + threadIdx.x) >> 6;
    if (wave >= N_NODES) return;
    const int lane = threadIdx.x & 63;
    const int sub = lane >> 4, l = lane & 15;
    const int r = wave;
    const int beg = (r == 0) ? 0 : endoff[r - 1];
    const int end = endoff[r];

    float4 acc = {0.f, 0.f, 0.f, 0.f};
    int it = beg + sub;
    for (; it + 12 < end; it += 16) {
        const int2 ea = cv[it];
        const int2 eb = cv[it + 4];
        const int2 ec = cv[it + 8];
        const int2 ed = cv[it + 12];
        const float4 xa = *reinterpret_cast<const float4*>(x + (size_t)(ea.x & 0xFFFFF) * FDIM + l * 4);
        const float4 xb = *reinterpret_cast<const float4*>(x + (size_t)(eb.x & 0xFFFFF) * FDIM + l * 4);
        const float4 xc = *reinterpret_cast<const float4*>(x + (size_t)(ec.x & 0xFFFFF) * FDIM + l * 4);
        const float4 xd = *reinterpret_cast<const float4*>(x + (size_t)(ed.x & 0xFFFFF) * FDIM + l * 4);
        const float va = __int_as_float(ea.y);
        const float vb = __int_as_float(eb.y);
        const float vc = __int_as_float(ec.y);
        const float vd = __int_as_float(ed.y);
        acc.x += va * xa.x; acc.y += va * xa.y; acc.z += va * xa.z; acc.w += va * xa.w;
        acc.x += vb * xb.x; acc.y += vb * xb.y; acc.z += vb * xb.z; acc.w += vb * xb.w;
        acc.x += vc * xc.x; acc.y += vc * xc.y; acc.z += vc * xc.z; acc.w += vc * xc.w;
        acc.x += vd * xd.x; acc.y += vd * xd.y; acc.z += vd * xd.z; acc.w += vd * xd.w;
    }
    for (; it < end; it += 4) {
        const int2 e = cv[it];
        const float v = __int_as_float(e.y);
        const float4 xv = *reinterpret_cast<const float4*>(x + (size_t)(e.x & 0xFFFFF) * FDIM + l * 4);
        acc.x += v * xv.x; acc.y += v * xv.y; acc.z += v * xv.z; acc.w += v * xv.w;
    }
    #pragma unroll
    for (int off = 16; off < 64; off <<= 1) {
        acc.x += __shfl_xor(acc.x, off);
        acc.y += __shfl_xor(acc.y, off);
        acc.z += __shfl_xor(acc.z, off);
        acc.w += __shfl_xor(acc.w, off);
    }
    if (sub == 0)
        *reinterpret_cast<float4*>(out + (size_t)r * FDIM + l * 4) = acc;
}

// ============ SpMM over CSR, bf16 x: one 16-lane subgroup OWNS one row ============
// No cross-subgroup shuffle reduction; wave retires 4 rows. 4-way unrolled
// independent gather streams per subgroup keep 16 gathers in flight per wave.
__device__ __forceinline__ float bf2f(unsigned short h) {
    return __uint_as_float((unsigned int)h << 16);
}

__global__ __launch_bounds__(256) void spmm_csr_h(
    const unsigned short* __restrict__ xh, const int* __restrict__ endoff,
    const int2* __restrict__ cv, float* __restrict__ out)
{
    const int sg = (blockIdx.x * 256 + threadIdx.x) >> 4;   // subgroup id == row
    if (sg >= N_NODES) return;
    const int l = threadIdx.x & 15;
    const int r = sg;
    const int beg = (r == 0) ? 0 : endoff[r - 1];
    const int end = endoff[r];

    float4 acc = {0.f, 0.f, 0.f, 0.f};
    int it = beg;
    for (; it + 3 < end; it += 4) {
        const int2 ea = cv[it];
        const int2 eb = cv[it + 1];
        const int2 ec = cv[it + 2];
        const int2 ed = cv[it + 3];
        const ushort4 xa = *reinterpret_cast<const ushort4*>(xh + (size_t)(ea.x & 0xFFFFF) * FDIM + l * 4);
        const ushort4 xb = *reinterpret_cast<const ushort4*>(xh + (size_t)(eb.x & 0xFFFFF) * FDIM + l * 4);
        const ushort4 xc = *reinterpret_cast<const ushort4*>(xh + (size_t)(ec.x & 0xFFFFF) * FDIM + l * 4);
        const ushort4 xd = *reinterpret_cast<const ushort4*>(xh + (size_t)(ed.x & 0xFFFFF) * FDIM + l * 4);
        const float va = __int_as_float(ea.y);
        const float vb = __int_as_float(eb.y);
        const float vc = __int_as_float(ec.y);
        const float vd = __int_as_float(ed.y);
        acc.x += va * bf2f(xa.x); acc.y += va * bf2f(xa.y); acc.z += va * bf2f(xa.z); acc.w += va * bf2f(xa.w);
        acc.x += vb * bf2f(xb.x); acc.y += vb * bf2f(xb.y); acc.z += vb * bf2f(xb.z); acc.w += vb * bf2f(xb.w);
        acc.x += vc * bf2f(xc.x); acc.y += vc * bf2f(xc.y); acc.z += vc * bf2f(xc.z); acc.w += vc * bf2f(xc.w);
        acc.x += vd * bf2f(xd.x); acc.y += vd * bf2f(xd.y); acc.z += vd * bf2f(xd.z); acc.w += vd * bf2f(xd.w);
    }
    for (; it < end; ++it) {
        const int2 e = cv[it];
        const float v = __int_as_float(e.y);
        const ushort4 xv = *reinterpret_cast<const ushort4*>(xh + (size_t)(e.x & 0xFFFFF) * FDIM + l * 4);
        acc.x += v * bf2f(xv.x); acc.y += v * bf2f(xv.y); acc.z += v * bf2f(xv.z); acc.w += v * bf2f(xv.w);
    }

    *reinterpret_cast<float4*>(out + (size_t)r * FDIM + l * 4) = acc;
}

// ============ GEMM + bias + L2 normalize (verified) ============
__global__ __launch_bounds__(256) void gemm_norm(
    float* __restrict__ io, const float* __restrict__ W,
    const float* __restrict__ bias)
{
    __shared__ float4 Wl[64][16];
    __shared__ float4 bl[16];
    __shared__ float  s[4][4][68];

    const int t = threadIdx.x;
    for (int i = t; i < 64 * 16; i += 256)
        ((float4*)Wl)[i] = ((const float4*)W)[i];
    if (t < 16) bl[t] = ((const float4*)bias)[t];

    const int wid  = t >> 6;
    const int lane = t & 63;
    const int sub  = lane >> 4;
    const int l    = lane & 15;
    const long base = (long)blockIdx.x * 16 + wid * 4;

    float4 sv = *reinterpret_cast<const float4*>(io + base * FDIM + lane * 4);
    *reinterpret_cast<float4*>(&s[wid][lane >> 4][(lane & 15) * 4]) = sv;
    __syncthreads();

    float4 acc = {0.f, 0.f, 0.f, 0.f};
    const float* srow = s[wid][sub];
    #pragma unroll
    for (int k = 0; k < FDIM; ++k) {
        const float a = srow[k];
        const float4 w = Wl[k][l];
        acc.x += a * w.x; acc.y += a * w.y; acc.z += a * w.z; acc.w += a * w.w;
    }
    const float4 b = bl[l];
    acc.x += b.x; acc.y += b.y; acc.z += b.z; acc.w += b.w;

    float p = acc.x*acc.x + acc.y*acc.y + acc.z*acc.z + acc.w*acc.w;
    #pragma unroll
    for (int off = 1; off < 16; off <<= 1)
        p += __shfl_xor(p, off);
    const float inv = 1.0f / sqrtf(p);
    acc.x *= inv; acc.y *= inv; acc.z *= inv; acc.w *= inv;

    *reinterpret_cast<float4*>(io + (base + sub) * FDIM + l * 4) = acc;
}

extern "C" void kernel_launch(void* const* d_in, const int* in_sizes, int n_in,
                              void* d_out, int out_size, void* d_ws, size_t ws_size,
                              hipStream_t stream) {
    const float* x    = (const float*)d_in[0];
    const int*   erow = (const int*)d_in[1];
    const int*   ecol = (const int*)d_in[2];
    const float* eval = (const float*)d_in[3];
    const float* W    = (const float*)d_in[4];
    const float* bias = (const float*)d_in[5];
    float* out = (float*)d_out;
    const int n_edges = in_sizes[1];

    const int nblk = (n_edges + EDGES_PER_BLK - 1) / EDGES_PER_BLK;   // 196
    const size_t need = (size_t)WS_CV_OFF + (size_t)n_edges * sizeof(int2);
    const size_t need_bf16 = (size_t)WS_XH_OFF + (size_t)N_NODES * FDIM * sizeof(short);
    const bool cnts_fit =
        (size_t)NBUCK * nblk * sizeof(int) <= WS_BBASE_OFF && nblk <= 256;

    if (ws_size >= need && cnts_fit) {
        int*  cnts   = (int*)d_ws;                              // dies after bin_pass2
        int*  endoff = (int*)d_ws;                              // born in sort_bucket
        int*  bbase  = (int*)((char*)d_ws + WS_BBASE_OFF);
        int*  btot   = (int*)((char*)d_ws + WS_BTOT_OFF);
        int2* cvbin  = (int2*)((char*)d_ws + WS_CV_OFF);
        unsigned short* xh = (unsigned short*)((char*)d_ws + WS_XH_OFF);
        const bool use_bf16 = (ws_size >= need_bf16);

        if (use_bf16)
            convert_x<<<(N_NODES * FDIM) / (256 * 8), 256, 0, stream>>>(x, xh);
        count_blocks<<<nblk, 1024, 0, stream>>>(erow, cnts, n_edges, nblk);
        scan_within_bucket<<<NBUCK, 256, 0, stream>>>(cnts, btot, nblk);
        scan_btot<<<1, 1024, 0, stream>>>(btot, bbase, n_edges);
        bin_pass2<<<nblk, 1024, 0, stream>>>(erow, ecol, eval, cnts, bbase, cvbin,
                                             n_edges, nblk);
        sort_bucket<<<NBUCK, 256, 0, stream>>>(bbase, cvbin, endoff);
        if (use_bf16)
            spmm_csr_h<<<((N_NODES * 16) + 255) / 256, 256, 0, stream>>>(xh, endoff, cvbin, out);
        else
            spmm_csr<<<(N_NODES + 3) / 4, 256, 0, stream>>>(x, endoff, cvbin, out);
    } else {
        hipMemsetAsync(out, 0, (size_t)N_NODES * FDIM * sizeof(float), stream);
        long threads = (long)n_edges * 16;
        spmm_atomic<<<(int)((threads + 255) / 256), 256, 0, stream>>>(
            x, erow, ecol, eval, out, n_edges);
    }

    gemm_norm<<<N_NODES / 16, 256, 0, stream>>>(out, W, bias);
}

// Round 14
// 102.732 us; speedup vs baseline: 4.2589x; 1.0806x over previous
//
#include <hip/hip_runtime.h>

#define N_NODES 100000
#define FDIM 64
#define BROWS 128                               // rows per bucket
#define NBUCK ((N_NODES + BROWS - 1) / BROWS)   // 782
#define EDGES_PER_BLK 8192
#define BCAP 3072                               // LDS sort capacity (mean 2046, sd 45)

// ---------------- ws layout ----------------
// cnts   : off 0       NBUCK*nblk ints (within-bucket exclusive prefixes); dead after bin
// endoff : off 0       N_NODES ints (CSR row-end offsets; born in sort_bucket after cnts dies)
// bbase  : off 656 KB  NBUCK+1 ints (bucket bases + sentinel)
// btot   : off 672 KB  NBUCK ints (bucket totals)
// cvbin  : off 1 MB    n_edges int2 {col | rowlo<<20, float_bits(val)}
// yh     : off 14 MB   N_NODES*FDIM bf16 of y = x@W (only if ws_size permits)
#define WS_BBASE_OFF (656u * 1024u)
#define WS_BTOT_OFF  (672u * 1024u)
#define WS_CV_OFF    (1024u * 1024u)
#define WS_XH_OFF    (14u * 1024u * 1024u)

__device__ __forceinline__ unsigned short f2bf(float f) {
    unsigned int u = __float_as_uint(f);
    return (unsigned short)((u + 0x7FFFu + ((u >> 16) & 1u)) >> 16);
}
__device__ __forceinline__ float bf2f(unsigned short h) {
    return __uint_as_float((unsigned int)h << 16);
}

// ============ fallback (round-4 verified): fp32 HW atomics ============
__global__ __launch_bounds__(256) void spmm_atomic(
    const float* __restrict__ x, const int* __restrict__ erow,
    const int* __restrict__ ecol, const float* __restrict__ eval,
    float* __restrict__ out, int n_edges)
{
    int tid = blockIdx.x * 256 + threadIdx.x;
    int e = tid >> 4, l = tid & 15;
    if (e >= n_edges) return;
    int row = erow[e], col = ecol[e];
    float v = eval[e];
    const float4 xv = *reinterpret_cast<const float4*>(x + (size_t)col * FDIM + l * 4);
    float* dst = out + (size_t)row * FDIM + l * 4;
    unsafeAtomicAdd(dst + 0, v * xv.x);
    unsafeAtomicAdd(dst + 1, v * xv.y);
    unsafeAtomicAdd(dst + 2, v * xv.z);
    unsafeAtomicAdd(dst + 3, v * xv.w);
}

// ============ y = x @ W, output bf16 (replaces convert_x; no bias) ============
__global__ __launch_bounds__(256) void gemm_xw(
    const float* __restrict__ x, const float* __restrict__ W,
    unsigned short* __restrict__ yh)
{
    __shared__ float4 Wl[64][16];        // W[k][:] as 16 float4
    __shared__ float  s[4][4][68];       // [wave][row-sub][k]

    const int t = threadIdx.x;
    for (int i = t; i < 64 * 16; i += 256)
        ((float4*)Wl)[i] = ((const float4*)W)[i];

    const int wid  = t >> 6;
    const int lane = t & 63;
    const int sub  = lane >> 4;
    const int l    = lane & 15;
    const long base = (long)blockIdx.x * 16 + wid * 4;

    float4 sv = *reinterpret_cast<const float4*>(x + base * FDIM + lane * 4);
    *reinterpret_cast<float4*>(&s[wid][lane >> 4][(lane & 15) * 4]) = sv;
    __syncthreads();

    float4 acc = {0.f, 0.f, 0.f, 0.f};
    const float* srow = s[wid][sub];
    #pragma unroll
    for (int k = 0; k < FDIM; ++k) {
        const float a = srow[k];
        const float4 w = Wl[k][l];
        acc.x += a * w.x; acc.y += a * w.y; acc.z += a * w.z; acc.w += a * w.w;
    }
    ushort4 h;
    h.x = f2bf(acc.x); h.y = f2bf(acc.y); h.z = f2bf(acc.z); h.w = f2bf(acc.w);
    *reinterpret_cast<ushort4*>(yh + (size_t)(base + sub) * FDIM + l * 4) = h;
}

// ============ per-(bucket,block) counts: 1024 threads/chunk (round-12 verified) ============
__global__ __launch_bounds__(1024) void count_blocks(
    const int* __restrict__ erow, int* __restrict__ cnts,
    int n_edges, int nblk)
{
    __shared__ int cnt[NBUCK];
    const int blk = blockIdx.x, t = threadIdx.x;
    for (int i = t; i < NBUCK; i += 1024) cnt[i] = 0;
    __syncthreads();
    const int beg = blk * EDGES_PER_BLK;
    const int end = min(beg + EDGES_PER_BLK, n_edges);
    for (int i = beg + t; i < end; i += 1024)
        atomicAdd(&cnt[erow[i] >> 7], 1);
    __syncthreads();
    for (int b = t; b < NBUCK; b += 1024)
        cnts[b * nblk + blk] = cnt[b];
}

// ============ within-bucket exclusive scan (782 blocks; round-9 verified) ============
__global__ __launch_bounds__(256) void scan_within_bucket(
    int* __restrict__ cnts, int* __restrict__ btot, int nblk)
{
    __shared__ int ssum[256];
    const int b = blockIdx.x, t = threadIdx.x;
    const int c = (t < nblk) ? cnts[b * nblk + t] : 0;
    ssum[t] = c;
    __syncthreads();
    for (int off = 1; off < 256; off <<= 1) {
        int v = (t >= off) ? ssum[t - off] : 0;
        __syncthreads();
        ssum[t] += v;
        __syncthreads();
    }
    if (t < nblk) cnts[b * nblk + t] = ssum[t] - c;   // exclusive
    if (t == 255) btot[b] = ssum[255];
}

// ============ scan of bucket totals -> bbase (round-9 verified) ============
__global__ __launch_bounds__(1024) void scan_btot(
    const int* __restrict__ btot, int* __restrict__ bbase, int n_edges)
{
    __shared__ int ssum[1024];
    const int t = threadIdx.x;
    const int v0 = (t < NBUCK) ? btot[t] : 0;
    ssum[t] = v0;
    __syncthreads();
    for (int off = 1; off < 1024; off <<= 1) {
        int v = (t >= off) ? ssum[t - off] : 0;
        __syncthreads();
        ssum[t] += v;
        __syncthreads();
    }
    if (t < NBUCK) bbase[t] = ssum[t] - v0;   // exclusive
    if (t == 0) bbase[NBUCK] = n_edges;       // sentinel
}

// ============ bin via block-private segments: 1024 threads/chunk (round-12 verified) ============
__global__ __launch_bounds__(1024) void bin_pass2(
    const int* __restrict__ erow, const int* __restrict__ ecol,
    const float* __restrict__ eval, const int* __restrict__ cnts,
    const int* __restrict__ bbase, int2* __restrict__ cvbin,
    int n_edges, int nblk)
{
    __shared__ int cur[NBUCK];
    const int blk = blockIdx.x, t = threadIdx.x;
    for (int b = t; b < NBUCK; b += 1024)
        cur[b] = bbase[b] + cnts[b * nblk + blk];
    __syncthreads();
    const int beg = blk * EDGES_PER_BLK;
    const int end = min(beg + EDGES_PER_BLK, n_edges);
    for (int i = beg + t; i < end; i += 1024) {
        int r = erow[i];
        int b = r >> 7;
        int pos = atomicAdd(&cur[b], 1);            // LDS atomic
        cvbin[pos] = make_int2(ecol[i] | ((r & 127) << 20), __float_as_int(eval[i]));
    }
}

// ============ per-bucket in-place counting sort (round-7/8/9 verified) ============
__global__ __launch_bounds__(256) void sort_bucket(
    const int* __restrict__ bbase, int2* __restrict__ cvbin,
    int* __restrict__ endoff)
{
    __shared__ int2 se[BCAP];        // 24 KB
    __shared__ int  hcnt[BROWS];
    __shared__ int  tmp[BROWS];
    __shared__ int  hoff[BROWS];
    const int b = blockIdx.x, t = threadIdx.x;
    const int beg = bbase[b];
    const int end = bbase[b + 1];
    const int n = end - beg;         // ~2046 +- 45 for this input; BCAP=3072

    for (int i = t; i < n; i += 256) se[i] = cvbin[beg + i];
    if (t < BROWS) hcnt[t] = 0;
    __syncthreads();

    for (int i = t; i < n; i += 256) atomicAdd(&hcnt[se[i].x >> 20], 1);
    __syncthreads();

    if (t < BROWS) tmp[t] = hcnt[t];
    __syncthreads();
    for (int off = 1; off < BROWS; off <<= 1) {
        int val = (t < BROWS && t >= off) ? tmp[t - off] : 0;
        __syncthreads();
        if (t < BROWS) tmp[t] += val;
        __syncthreads();
    }
    if (t < BROWS) hoff[t] = tmp[t] - hcnt[t];
    __syncthreads();

    for (int i = t; i < n; i += 256) {
        int2 e = se[i];
        int pos = atomicAdd(&hoff[e.x >> 20], 1);
        cvbin[beg + pos] = e;
    }
    __syncthreads();

    if (t < BROWS) {
        int row = b * BROWS + t;
        if (row < N_NODES) endoff[row] = beg + hoff[t];
    }
}

// ============ SpMM over CSR, fp32 x (ws-small path; round-10 verified) ============
__global__ __launch_bounds__(256) void spmm_csr(
    const float* __restrict__ x, const int* __restrict__ endoff,
    const int2* __restrict__ cv, float* __restrict__ out)
{
    const int wave = (blockIdx.x * 256 + threadIdx.x) >> 6;
    if (wave >= N_NODES) return;
    const int lane = threadIdx.x & 63;
    const int sub = lane >> 4, l = lane & 15;
    const int r = wave;
    const int beg = (r == 0) ? 0 : endoff[r - 1];
    const int end = endoff[r];

    float4 acc = {0.f, 0.f, 0.f, 0.f};
    int it = beg + sub;
    for (; it + 12 < end; it += 16) {
        const int2 ea = cv[it];
        const int2 eb = cv[it + 4];
        const int2 ec = cv[it + 8];
        const int2 ed = cv[it + 12];
        const float4 xa = *reinterpret_cast<const float4*>(x + (size_t)(ea.x & 0xFFFFF) * FDIM + l * 4);
        const float4 xb = *reinterpret_cast<const float4*>(x + (size_t)(eb.x & 0xFFFFF) * FDIM + l * 4);
        const float4 xc = *reinterpret_cast<const float4*>(x + (size_t)(ec.x & 0xFFFFF) * FDIM + l * 4);
        const float4 xd = *reinterpret_cast<const float4*>(x + (size_t)(ed.x & 0xFFFFF) * FDIM + l * 4);
        const float va = __int_as_float(ea.y);
        const float vb = __int_as_float(eb.y);
        const float vc = __int_as_float(ec.y);
        const float vd = __int_as_float(ed.y);
        acc.x += va * xa.x; acc.y += va * xa.y; acc.z += va * xa.z; acc.w += va * xa.w;
        acc.x += vb * xb.x; acc.y += vb * xb.y; acc.z += vb * xb.z; acc.w += vb * xb.w;
        acc.x += vc * xc.x; acc.y += vc * xc.y; acc.z += vc * xc.z; acc.w += vc * xc.w;
        acc.x += vd * xd.x; acc.y += vd * xd.y; acc.z += vd * xd.z; acc.w += vd * xd.w;
    }
    for (; it < end; it += 4) {
        const int2 e = cv[it];
        const float v = __int_as_float(e.y);
        const float4 xv = *reinterpret_cast<const float4*>(x + (size_t)(e.x & 0xFFFFF) * FDIM + l * 4);
        acc.x += v * xv.x; acc.y += v * xv.y; acc.z += v * xv.z; acc.w += v * xv.w;
    }
    #pragma unroll
    for (int off = 16; off < 64; off <<= 1) {
        acc.x += __shfl_xor(acc.x, off);
        acc.y += __shfl_xor(acc.y, off);
        acc.z += __shfl_xor(acc.z, off);
        acc.w += __shfl_xor(acc.w, off);
    }
    if (sub == 0)
        *reinterpret_cast<float4*>(out + (size_t)r * FDIM + l * 4) = acc;
}

// ============ fused SpMM + bias + L2 normalize over y=xW (bf16) ============
// One 16-lane subgroup owns one row (round-13 verified structure).
__global__ __launch_bounds__(256) void spmm_fused(
    const unsigned short* __restrict__ yh, const int* __restrict__ endoff,
    const int2* __restrict__ cv, const float* __restrict__ bias,
    float* __restrict__ out)
{
    const int sg = (blockIdx.x * 256 + threadIdx.x) >> 4;   // subgroup id == row
    if (sg >= N_NODES) return;
    const int l = threadIdx.x & 15;
    const int beg = (sg == 0) ? 0 : endoff[sg - 1];
    const int end = endoff[sg];

    float4 acc = {0.f, 0.f, 0.f, 0.f};
    int it = beg;
    for (; it + 3 < end; it += 4) {
        const int2 ea = cv[it];
        const int2 eb = cv[it + 1];
        const int2 ec = cv[it + 2];
        const int2 ed = cv[it + 3];
        const ushort4 xa = *reinterpret_cast<const ushort4*>(yh + (size_t)(ea.x & 0xFFFFF) * FDIM + l * 4);
        const ushort4 xb = *reinterpret_cast<const ushort4*>(yh + (size_t)(eb.x & 0xFFFFF) * FDIM + l * 4);
        const ushort4 xc = *reinterpret_cast<const ushort4*>(yh + (size_t)(ec.x & 0xFFFFF) * FDIM + l * 4);
        const ushort4 xd = *reinterpret_cast<const ushort4*>(yh + (size_t)(ed.x & 0xFFFFF) * FDIM + l * 4);
        const float va = __int_as_float(ea.y);
        const float vb = __int_as_float(eb.y);
        const float vc = __int_as_float(ec.y);
        const float vd = __int_as_float(ed.y);
        acc.x += va * bf2f(xa.x); acc.y += va * bf2f(xa.y); acc.z += va * bf2f(xa.z); acc.w += va * bf2f(xa.w);
        acc.x += vb * bf2f(xb.x); acc.y += vb * bf2f(xb.y); acc.z += vb * bf2f(xb.z); acc.w += vb * bf2f(xb.w);
        acc.x += vc * bf2f(xc.x); acc.y += vc * bf2f(xc.y); acc.z += vc * bf2f(xc.z); acc.w += vc * bf2f(xc.w);
        acc.x += vd * bf2f(xd.x); acc.y += vd * bf2f(xd.y); acc.z += vd * bf2f(xd.z); acc.w += vd * bf2f(xd.w);
    }
    for (; it < end; ++it) {
        const int2 e = cv[it];
        const float v = __int_as_float(e.y);
        const ushort4 xv = *reinterpret_cast<const ushort4*>(yh + (size_t)(e.x & 0xFFFFF) * FDIM + l * 4);
        acc.x += v * bf2f(xv.x); acc.y += v * bf2f(xv.y); acc.z += v * bf2f(xv.z); acc.w += v * bf2f(xv.w);
    }

    // + bias
    const float4 b = *reinterpret_cast<const float4*>(bias + l * 4);
    acc.x += b.x; acc.y += b.y; acc.z += b.z; acc.w += b.w;

    // row L2 norm across the 16-lane subgroup
    float p = acc.x * acc.x + acc.y * acc.y + acc.z * acc.z + acc.w * acc.w;
    #pragma unroll
    for (int off = 1; off < 16; off <<= 1)
        p += __shfl_xor(p, off);
    const float inv = 1.0f / sqrtf(p);
    acc.x *= inv; acc.y *= inv; acc.z *= inv; acc.w *= inv;

    *reinterpret_cast<float4*>(out + (size_t)sg * FDIM + l * 4) = acc;
}

// ============ GEMM + bias + L2 normalize (fallback epilogue; verified) ============
__global__ __launch_bounds__(256) void gemm_norm(
    float* __restrict__ io, const float* __restrict__ W,
    const float* __restrict__ bias)
{
    __shared__ float4 Wl[64][16];
    __shared__ float4 bl[16];
    __shared__ float  s[4][4][68];

    const int t = threadIdx.x;
    for (int i = t; i < 64 * 16; i += 256)
        ((float4*)Wl)[i] = ((const float4*)W)[i];
    if (t < 16) bl[t] = ((const float4*)bias)[t];

    const int wid  = t >> 6;
    const int lane = t & 63;
    const int sub  = lane >> 4;
    const int l    = lane & 15;
    const long base = (long)blockIdx.x * 16 + wid * 4;

    float4 sv = *reinterpret_cast<const float4*>(io + base * FDIM + lane * 4);
    *reinterpret_cast<float4*>(&s[wid][lane >> 4][(lane & 15) * 4]) = sv;
    __syncthreads();

    float4 acc = {0.f, 0.f, 0.f, 0.f};
    const float* srow = s[wid][sub];
    #pragma unroll
    for (int k = 0; k < FDIM; ++k) {
        const float a = srow[k];
        const float4 w = Wl[k][l];
        acc.x += a * w.x; acc.y += a * w.y; acc.z += a * w.z; acc.w += a * w.w;
    }
    const float4 b = bl[l];
    acc.x += b.x; acc.y += b.y; acc.z += b.z; acc.w += b.w;

    float p = acc.x*acc.x + acc.y*acc.y + acc.z*acc.z + acc.w*acc.w;
    #pragma unroll
    for (int off = 1; off < 16; off <<= 1)
        p += __shfl_xor(p, off);
    const float inv = 1.0f / sqrtf(p);
    acc.x *= inv; acc.y *= inv; acc.z *= inv; acc.w *= inv;

    *reinterpret_cast<float4*>(io + (base + sub) * FDIM + l * 4) = acc;
}

extern "C" void kernel_launch(void* const* d_in, const int* in_sizes, int n_in,
                              void* d_out, int out_size, void* d_ws, size_t ws_size,
                              hipStream_t stream) {
    const float* x    = (const float*)d_in[0];
    const int*   erow = (const int*)d_in[1];
    const int*   ecol = (const int*)d_in[2];
    const float* eval = (const float*)d_in[3];
    const float* W    = (const float*)d_in[4];
    const float* bias = (const float*)d_in[5];
    float* out = (float*)d_out;
    const int n_edges = in_sizes[1];

    const int nblk = (n_edges + EDGES_PER_BLK - 1) / EDGES_PER_BLK;   // 196
    const size_t need = (size_t)WS_CV_OFF + (size_t)n_edges * sizeof(int2);
    const size_t need_bf16 = (size_t)WS_XH_OFF + (size_t)N_NODES * FDIM * sizeof(short);
    const bool cnts_fit =
        (size_t)NBUCK * nblk * sizeof(int) <= WS_BBASE_OFF && nblk <= 256;

    if (ws_size >= need && cnts_fit) {
        int*  cnts   = (int*)d_ws;                              // dies after bin_pass2
        int*  endoff = (int*)d_ws;                              // born in sort_bucket
        int*  bbase  = (int*)((char*)d_ws + WS_BBASE_OFF);
        int*  btot   = (int*)((char*)d_ws + WS_BTOT_OFF);
        int2* cvbin  = (int2*)((char*)d_ws + WS_CV_OFF);
        unsigned short* yh = (unsigned short*)((char*)d_ws + WS_XH_OFF);
        const bool use_bf16 = (ws_size >= need_bf16);

        if (use_bf16)
            gemm_xw<<<N_NODES / 16, 256, 0, stream>>>(x, W, yh);
        count_blocks<<<nblk, 1024, 0, stream>>>(erow, cnts, n_edges, nblk);
        scan_within_bucket<<<NBUCK, 256, 0, stream>>>(cnts, btot, nblk);
        scan_btot<<<1, 1024, 0, stream>>>(btot, bbase, n_edges);
        bin_pass2<<<nblk, 1024, 0, stream>>>(erow, ecol, eval, cnts, bbase, cvbin,
                                             n_edges, nblk);
        sort_bucket<<<NBUCK, 256, 0, stream>>>(bbase, cvbin, endoff);
        if (use_bf16) {
            spmm_fused<<<((N_NODES * 16) + 255) / 256, 256, 0, stream>>>(
                yh, endoff, cvbin, bias, out);
        } else {
            spmm_csr<<<(N_NODES + 3) / 4, 256, 0, stream>>>(x, endoff, cvbin, out);
            gemm_norm<<<N_NODES / 16, 256, 0, stream>>>(out, W, bias);
        }
    } else {
        hipMemsetAsync(out, 0, (size_t)N_NODES * FDIM * sizeof(float), stream);
        long threads = (long)n_edges * 16;
        spmm_atomic<<<(int)((threads + 255) / 256), 256, 0, stream>>>(
            x, erow, ecol, eval, out, n_edges);
        gemm_norm<<<N_NODES / 16, 256, 0, stream>>>(out, W, bias);
    }
}

// Round 15
// 100.591 us; speedup vs baseline: 4.3495x; 1.0213x over previous
//
#include <hip/hip_runtime.h>

#define N_NODES 100000
#define FDIM 64
#define BROWS 64                                // rows per bucket
#define NBUCK ((N_NODES + BROWS - 1) / BROWS)   // 1563
#define EDGES_PER_BLK 16384
#define BCAP 1536                               // LDS sort capacity (mean 1024, sd 32)

// ---------------- ws layout ----------------
// cnts   : off 0       NBUCK*nblk ints (613 KB; within-bucket exclusive prefixes)
// bbase  : off 656 KB  NBUCK+1 ints (bucket bases + sentinel)
// btot   : off 672 KB  NBUCK ints (bucket totals)
// cvbin  : off 1 MB    n_edges int2 {col | rowlo<<20, float_bits(val)}
// yh     : off 14 MB   N_NODES*FDIM bf16 of y = x@W
#define WS_BBASE_OFF (656u * 1024u)
#define WS_BTOT_OFF  (672u * 1024u)
#define WS_CV_OFF    (1024u * 1024u)
#define WS_XH_OFF    (14u * 1024u * 1024u)

__device__ __forceinline__ unsigned short f2bf(float f) {
    unsigned int u = __float_as_uint(f);
    return (unsigned short)((u + 0x7FFFu + ((u >> 16) & 1u)) >> 16);
}
__device__ __forceinline__ float bf2f(unsigned short h) {
    return __uint_as_float((unsigned int)h << 16);
}

// ============ fallback (round-4 verified): fp32 HW atomics ============
__global__ __launch_bounds__(256) void spmm_atomic(
    const float* __restrict__ x, const int* __restrict__ erow,
    const int* __restrict__ ecol, const float* __restrict__ eval,
    float* __restrict__ out, int n_edges)
{
    int tid = blockIdx.x * 256 + threadIdx.x;
    int e = tid >> 4, l = tid & 15;
    if (e >= n_edges) return;
    int row = erow[e], col = ecol[e];
    float v = eval[e];
    const float4 xv = *reinterpret_cast<const float4*>(x + (size_t)col * FDIM + l * 4);
    float* dst = out + (size_t)row * FDIM + l * 4;
    unsafeAtomicAdd(dst + 0, v * xv.x);
    unsafeAtomicAdd(dst + 1, v * xv.y);
    unsafeAtomicAdd(dst + 2, v * xv.z);
    unsafeAtomicAdd(dst + 3, v * xv.w);
}

// ============ y = x @ W, output bf16 (round-14 verified) ============
__global__ __launch_bounds__(256) void gemm_xw(
    const float* __restrict__ x, const float* __restrict__ W,
    unsigned short* __restrict__ yh)
{
    __shared__ float4 Wl[64][16];
    __shared__ float  s[4][4][68];

    const int t = threadIdx.x;
    for (int i = t; i < 64 * 16; i += 256)
        ((float4*)Wl)[i] = ((const float4*)W)[i];

    const int wid  = t >> 6;
    const int lane = t & 63;
    const int sub  = lane >> 4;
    const int l    = lane & 15;
    const long base = (long)blockIdx.x * 16 + wid * 4;

    float4 sv = *reinterpret_cast<const float4*>(x + base * FDIM + lane * 4);
    *reinterpret_cast<float4*>(&s[wid][lane >> 4][(lane & 15) * 4]) = sv;
    __syncthreads();

    float4 acc = {0.f, 0.f, 0.f, 0.f};
    const float* srow = s[wid][sub];
    #pragma unroll
    for (int k = 0; k < FDIM; ++k) {
        const float a = srow[k];
        const float4 w = Wl[k][l];
        acc.x += a * w.x; acc.y += a * w.y; acc.z += a * w.z; acc.w += a * w.w;
    }
    ushort4 h;
    h.x = f2bf(acc.x); h.y = f2bf(acc.y); h.z = f2bf(acc.z); h.w = f2bf(acc.w);
    *reinterpret_cast<ushort4*>(yh + (size_t)(base + sub) * FDIM + l * 4) = h;
}

// ============ per-(bucket,block) counts (round-12 structure, BROWS=64) ============
__global__ __launch_bounds__(1024) void count_blocks(
    const int* __restrict__ erow, int* __restrict__ cnts,
    int n_edges, int nblk)
{
    __shared__ int cnt[NBUCK];
    const int blk = blockIdx.x, t = threadIdx.x;
    for (int i = t; i < NBUCK; i += 1024) cnt[i] = 0;
    __syncthreads();
    const int beg = blk * EDGES_PER_BLK;
    const int end = min(beg + EDGES_PER_BLK, n_edges);
    for (int i = beg + t; i < end; i += 1024)
        atomicAdd(&cnt[erow[i] >> 6], 1);
    __syncthreads();
    for (int b = t; b < NBUCK; b += 1024)
        cnts[b * nblk + blk] = cnt[b];
}

// ============ within-bucket exclusive scan (round-9 verified; nblk<=256) ============
__global__ __launch_bounds__(256) void scan_within_bucket(
    int* __restrict__ cnts, int* __restrict__ btot, int nblk)
{
    __shared__ int ssum[256];
    const int b = blockIdx.x, t = threadIdx.x;
    const int c = (t < nblk) ? cnts[b * nblk + t] : 0;
    ssum[t] = c;
    __syncthreads();
    for (int off = 1; off < 256; off <<= 1) {
        int v = (t >= off) ? ssum[t - off] : 0;
        __syncthreads();
        ssum[t] += v;
        __syncthreads();
    }
    if (t < nblk) cnts[b * nblk + t] = ssum[t] - c;   // exclusive
    if (t == 255) btot[b] = ssum[255];
}

// ============ scan of bucket totals -> bbase (2 elems/thread; NBUCK<=2048) ============
__global__ __launch_bounds__(1024) void scan_btot(
    const int* __restrict__ btot, int* __restrict__ bbase, int n_edges)
{
    __shared__ int ssum[1024];
    const int t = threadIdx.x;
    const int i0 = 2 * t, i1 = 2 * t + 1;
    const int v0 = (i0 < NBUCK) ? btot[i0] : 0;
    const int v1 = (i1 < NBUCK) ? btot[i1] : 0;
    const int s = v0 + v1;
    ssum[t] = s;
    __syncthreads();
    for (int off = 1; off < 1024; off <<= 1) {
        int v = (t >= off) ? ssum[t - off] : 0;
        __syncthreads();
        ssum[t] += v;
        __syncthreads();
    }
    int base = ssum[t] - s;                    // exclusive
    if (i0 < NBUCK) bbase[i0] = base;
    if (i1 < NBUCK) bbase[i1] = base + v0;
    if (t == 0) bbase[NBUCK] = n_edges;        // sentinel
}

// ============ bin via block-private segments (round-12 structure) ============
__global__ __launch_bounds__(1024) void bin_pass2(
    const int* __restrict__ erow, const int* __restrict__ ecol,
    const float* __restrict__ eval, const int* __restrict__ cnts,
    const int* __restrict__ bbase, int2* __restrict__ cvbin,
    int n_edges, int nblk)
{
    __shared__ int cur[NBUCK];
    const int blk = blockIdx.x, t = threadIdx.x;
    for (int b = t; b < NBUCK; b += 1024)
        cur[b] = bbase[b] + cnts[b * nblk + blk];
    __syncthreads();
    const int beg = blk * EDGES_PER_BLK;
    const int end = min(beg + EDGES_PER_BLK, n_edges);
    for (int i = beg + t; i < end; i += 1024) {
        int r = erow[i];
        int b = r >> 6;
        int pos = atomicAdd(&cur[b], 1);            // LDS atomic
        cvbin[pos] = make_int2(ecol[i] | ((r & 63) << 20), __float_as_int(eval[i]));
    }
}

// ============ fused: LDS counting-sort + SpMM + bias + L2 norm ============
// One block per 64-row bucket; 16 subgroups of 16 lanes, 4 rows each.
__global__ __launch_bounds__(256) void sort_spmm(
    const int* __restrict__ bbase, const int2* __restrict__ cvbin,
    const unsigned short* __restrict__ yh, const float* __restrict__ bias,
    float* __restrict__ out)
{
    __shared__ int2 se[BCAP];          // 12 KB sorted edges
    __shared__ int  hcnt[BROWS];
    __shared__ int  scn[BROWS];
    __shared__ int  rowbeg[BROWS];
    __shared__ int  cur[BROWS];

    const int b = blockIdx.x, t = threadIdx.x;
    const int beg = bbase[b];
    const int end = bbase[b + 1];
    const int n = end - beg;
    const bool fits = (n <= BCAP);     // >16 sigma margin; safety path below

    if (t < BROWS) hcnt[t] = 0;
    __syncthreads();

    if (fits) {
        for (int i = t; i < n; i += 256)
            atomicAdd(&hcnt[(cvbin[beg + i].x >> 20) & 63], 1);
        __syncthreads();
        if (t < BROWS) scn[t] = hcnt[t];
        __syncthreads();
        for (int off = 1; off < BROWS; off <<= 1) {
            int v = (t < BROWS && t >= off) ? scn[t - off] : 0;
            __syncthreads();
            if (t < BROWS) scn[t] += v;
            __syncthreads();
        }
        if (t < BROWS) { rowbeg[t] = scn[t] - hcnt[t]; cur[t] = scn[t] - hcnt[t]; }
        __syncthreads();
        for (int i = t; i < n; i += 256) {
            int2 e = cvbin[beg + i];                       // L2-hot re-read
            int pos = atomicAdd(&cur[(e.x >> 20) & 63], 1);
            se[pos] = e;
        }
        __syncthreads();
    }

    const int sg = t >> 4, l = t & 15;
    #pragma unroll
    for (int rr = 0; rr < 4; ++rr) {
        const int r = sg + 16 * rr;                        // coalesced out writes
        const int row = b * BROWS + r;
        float4 acc = {0.f, 0.f, 0.f, 0.f};

        if (fits) {
            const int rb = rowbeg[r];
            const int re = rb + hcnt[r];
            int it = rb;
            for (; it + 3 < re; it += 4) {
                const int2 ea = se[it];
                const int2 eb = se[it + 1];
                const int2 ec = se[it + 2];
                const int2 ed = se[it + 3];
                const ushort4 xa = *reinterpret_cast<const ushort4*>(yh + (size_t)(ea.x & 0xFFFFF) * FDIM + l * 4);
                const ushort4 xb = *reinterpret_cast<const ushort4*>(yh + (size_t)(eb.x & 0xFFFFF) * FDIM + l * 4);
                const ushort4 xc = *reinterpret_cast<const ushort4*>(yh + (size_t)(ec.x & 0xFFFFF) * FDIM + l * 4);
                const ushort4 xd = *reinterpret_cast<const ushort4*>(yh + (size_t)(ed.x & 0xFFFFF) * FDIM + l * 4);
                const float va = __int_as_float(ea.y);
                const float vb = __int_as_float(eb.y);
                const float vc = __int_as_float(ec.y);
                const float vd = __int_as_float(ed.y);
                acc.x += va * bf2f(xa.x); acc.y += va * bf2f(xa.y); acc.z += va * bf2f(xa.z); acc.w += va * bf2f(xa.w);
                acc.x += vb * bf2f(xb.x); acc.y += vb * bf2f(xb.y); acc.z += vb * bf2f(xb.z); acc.w += vb * bf2f(xb.w);
                acc.x += vc * bf2f(xc.x); acc.y += vc * bf2f(xc.y); acc.z += vc * bf2f(xc.z); acc.w += vc * bf2f(xc.w);
                acc.x += vd * bf2f(xd.x); acc.y += vd * bf2f(xd.y); acc.z += vd * bf2f(xd.z); acc.w += vd * bf2f(xd.w);
            }
            for (; it < re; ++it) {
                const int2 e = se[it];
                const float v = __int_as_float(e.y);
                const ushort4 xv = *reinterpret_cast<const ushort4*>(yh + (size_t)(e.x & 0xFFFFF) * FDIM + l * 4);
                acc.x += v * bf2f(xv.x); acc.y += v * bf2f(xv.y); acc.z += v * bf2f(xv.z); acc.w += v * bf2f(xv.w);
            }
        } else {
            // safety path (never taken for this input): filter full segment from global
            for (int i = beg; i < end; ++i) {
                const int2 e = cvbin[i];
                if (((e.x >> 20) & 63) == r) {
                    const float v = __int_as_float(e.y);
                    const ushort4 xv = *reinterpret_cast<const ushort4*>(yh + (size_t)(e.x & 0xFFFFF) * FDIM + l * 4);
                    acc.x += v * bf2f(xv.x); acc.y += v * bf2f(xv.y); acc.z += v * bf2f(xv.z); acc.w += v * bf2f(xv.w);
                }
            }
        }

        const float4 bv = *reinterpret_cast<const float4*>(bias + l * 4);
        acc.x += bv.x; acc.y += bv.y; acc.z += bv.z; acc.w += bv.w;

        float p = acc.x * acc.x + acc.y * acc.y + acc.z * acc.z + acc.w * acc.w;
        #pragma unroll
        for (int off = 1; off < 16; off <<= 1)
            p += __shfl_xor(p, off);
        const float inv = 1.0f / sqrtf(p);
        acc.x *= inv; acc.y *= inv; acc.z *= inv; acc.w *= inv;

        if (row < N_NODES)
            *reinterpret_cast<float4*>(out + (size_t)row * FDIM + l * 4) = acc;
    }
}

// ============ GEMM + bias + L2 normalize (fallback epilogue; verified) ============
__global__ __launch_bounds__(256) void gemm_norm(
    float* __restrict__ io, const float* __restrict__ W,
    const float* __restrict__ bias)
{
    __shared__ float4 Wl[64][16];
    __shared__ float4 bl[16];
    __shared__ float  s[4][4][68];

    const int t = threadIdx.x;
    for (int i = t; i < 64 * 16; i += 256)
        ((float4*)Wl)[i] = ((const float4*)W)[i];
    if (t < 16) bl[t] = ((const float4*)bias)[t];

    const int wid  = t >> 6;
    const int lane = t & 63;
    const int sub  = lane >> 4;
    const int l    = lane & 15;
    const long base = (long)blockIdx.x * 16 + wid * 4;

    float4 sv = *reinterpret_cast<const float4*>(io + base * FDIM + lane * 4);
    *reinterpret_cast<float4*>(&s[wid][lane >> 4][(lane & 15) * 4]) = sv;
    __syncthreads();

    float4 acc = {0.f, 0.f, 0.f, 0.f};
    const float* srow = s[wid][sub];
    #pragma unroll
    for (int k = 0; k < FDIM; ++k) {
        const float a = srow[k];
        const float4 w = Wl[k][l];
        acc.x += a * w.x; acc.y += a * w.y; acc.z += a * w.z; acc.w += a * w.w;
    }
    const float4 b = bl[l];
    acc.x += b.x; acc.y += b.y; acc.z += b.z; acc.w += b.w;

    float p = acc.x*acc.x + acc.y*acc.y + acc.z*acc.z + acc.w*acc.w;
    #pragma unroll
    for (int off = 1; off < 16; off <<= 1)
        p += __shfl_xor(p, off);
    const float inv = 1.0f / sqrtf(p);
    acc.x *= inv; acc.y *= inv; acc.z *= inv; acc.w *= inv;

    *reinterpret_cast<float4*>(io + (base + sub) * FDIM + l * 4) = acc;
}

extern "C" void kernel_launch(void* const* d_in, const int* in_sizes, int n_in,
                              void* d_out, int out_size, void* d_ws, size_t ws_size,
                              hipStream_t stream) {
    const float* x    = (const float*)d_in[0];
    const int*   erow = (const int*)d_in[1];
    const int*   ecol = (const int*)d_in[2];
    const float* eval = (const float*)d_in[3];
    const float* W    = (const float*)d_in[4];
    const float* bias = (const float*)d_in[5];
    float* out = (float*)d_out;
    const int n_edges = in_sizes[1];

    const int nblk = (n_edges + EDGES_PER_BLK - 1) / EDGES_PER_BLK;   // 98
    const size_t need_bf16 = (size_t)WS_XH_OFF + (size_t)N_NODES * FDIM * sizeof(short);
    const bool cnts_fit =
        (size_t)NBUCK * nblk * sizeof(int) <= WS_BBASE_OFF && nblk <= 256;

    if (ws_size >= need_bf16 && cnts_fit) {
        int*  cnts   = (int*)d_ws;
        int*  bbase  = (int*)((char*)d_ws + WS_BBASE_OFF);
        int*  btot   = (int*)((char*)d_ws + WS_BTOT_OFF);
        int2* cvbin  = (int2*)((char*)d_ws + WS_CV_OFF);
        unsigned short* yh = (unsigned short*)((char*)d_ws + WS_XH_OFF);

        gemm_xw<<<N_NODES / 16, 256, 0, stream>>>(x, W, yh);
        count_blocks<<<nblk, 1024, 0, stream>>>(erow, cnts, n_edges, nblk);
        scan_within_bucket<<<NBUCK, 256, 0, stream>>>(cnts, btot, nblk);
        scan_btot<<<1, 1024, 0, stream>>>(btot, bbase, n_edges);
        bin_pass2<<<nblk, 1024, 0, stream>>>(erow, ecol, eval, cnts, bbase, cvbin,
                                             n_edges, nblk);
        sort_spmm<<<NBUCK, 256, 0, stream>>>(bbase, cvbin, yh, bias, out);
    } else {
        hipMemsetAsync(out, 0, (size_t)N_NODES * FDIM * sizeof(float), stream);
        long threads = (long)n_edges * 16;
        spmm_atomic<<<(int)((threads + 255) / 256), 256, 0, stream>>>(
            x, erow, ecol, eval, out, n_edges);
        gemm_norm<<<N_NODES / 16, 256, 0, stream>>>(out, W, bias);
    }
}

// Round 16
// 92.774 us; speedup vs baseline: 4.7160x; 1.0843x over previous
//
#include <hip/hip_runtime.h>

#define N_NODES 100000
#define FDIM 64
#define BROWS 64                                // rows per bucket
#define NBUCK ((N_NODES + BROWS - 1) / BROWS)   // 1563
#define EDGES_PER_BLK 8192
#define BCAP 1536                               // LDS sort capacity (mean 1024, sd 32)

// ---------------- ws layout ----------------
// cnts   : off 0       NBUCK*nblk ushort (613 KB; within-bucket exclusive prefixes)
// bbase  : off 656 KB  NBUCK+1 ints (bucket bases + sentinel)
// btot   : off 672 KB  NBUCK ints (bucket totals)
// cvbin  : off 1 MB    n_edges int2 {col | rowlo<<20, float_bits(val)}
// yh     : off 14 MB   N_NODES*FDIM bf16 of y = x@W
#define WS_BBASE_OFF (656u * 1024u)
#define WS_BTOT_OFF  (672u * 1024u)
#define WS_CV_OFF    (1024u * 1024u)
#define WS_XH_OFF    (14u * 1024u * 1024u)

__device__ __forceinline__ unsigned short f2bf(float f) {
    unsigned int u = __float_as_uint(f);
    return (unsigned short)((u + 0x7FFFu + ((u >> 16) & 1u)) >> 16);
}
__device__ __forceinline__ float bf2f(unsigned short h) {
    return __uint_as_float((unsigned int)h << 16);
}

// ============ fallback (round-4 verified): fp32 HW atomics ============
__global__ __launch_bounds__(256) void spmm_atomic(
    const float* __restrict__ x, const int* __restrict__ erow,
    const int* __restrict__ ecol, const float* __restrict__ eval,
    float* __restrict__ out, int n_edges)
{
    int tid = blockIdx.x * 256 + threadIdx.x;
    int e = tid >> 4, l = tid & 15;
    if (e >= n_edges) return;
    int row = erow[e], col = ecol[e];
    float v = eval[e];
    const float4 xv = *reinterpret_cast<const float4*>(x + (size_t)col * FDIM + l * 4);
    float* dst = out + (size_t)row * FDIM + l * 4;
    unsafeAtomicAdd(dst + 0, v * xv.x);
    unsafeAtomicAdd(dst + 1, v * xv.y);
    unsafeAtomicAdd(dst + 2, v * xv.z);
    unsafeAtomicAdd(dst + 3, v * xv.w);
}

// ============ y = x @ W, output bf16 (round-14 verified) ============
__global__ __launch_bounds__(256) void gemm_xw(
    const float* __restrict__ x, const float* __restrict__ W,
    unsigned short* __restrict__ yh)
{
    __shared__ float4 Wl[64][16];
    __shared__ float  s[4][4][68];

    const int t = threadIdx.x;
    for (int i = t; i < 64 * 16; i += 256)
        ((float4*)Wl)[i] = ((const float4*)W)[i];

    const int wid  = t >> 6;
    const int lane = t & 63;
    const int sub  = lane >> 4;
    const int l    = lane & 15;
    const long base = (long)blockIdx.x * 16 + wid * 4;

    float4 sv = *reinterpret_cast<const float4*>(x + base * FDIM + lane * 4);
    *reinterpret_cast<float4*>(&s[wid][lane >> 4][(lane & 15) * 4]) = sv;
    __syncthreads();

    float4 acc = {0.f, 0.f, 0.f, 0.f};
    const float* srow = s[wid][sub];
    #pragma unroll
    for (int k = 0; k < FDIM; ++k) {
        const float a = srow[k];
        const float4 w = Wl[k][l];
        acc.x += a * w.x; acc.y += a * w.y; acc.z += a * w.z; acc.w += a * w.w;
    }
    ushort4 h;
    h.x = f2bf(acc.x); h.y = f2bf(acc.y); h.z = f2bf(acc.z); h.w = f2bf(acc.w);
    *reinterpret_cast<ushort4*>(yh + (size_t)(base + sub) * FDIM + l * 4) = h;
}

// ============ per-(bucket,block) counts -> ushort (round-12 geometry) ============
__global__ __launch_bounds__(1024) void count_blocks(
    const int* __restrict__ erow, unsigned short* __restrict__ cnts,
    int n_edges, int nblk)
{
    __shared__ int cnt[NBUCK];
    const int blk = blockIdx.x, t = threadIdx.x;
    for (int i = t; i < NBUCK; i += 1024) cnt[i] = 0;
    __syncthreads();
    const int beg = blk * EDGES_PER_BLK;
    const int end = min(beg + EDGES_PER_BLK, n_edges);
    for (int i = beg + t; i < end; i += 1024)
        atomicAdd(&cnt[erow[i] >> 6], 1);
    __syncthreads();
    for (int b = t; b < NBUCK; b += 1024)
        cnts[b * nblk + blk] = (unsigned short)cnt[b];
}

// ============ within-bucket exclusive scan over ushort counts ============
__global__ __launch_bounds__(256) void scan_within_bucket(
    unsigned short* __restrict__ cnts, int* __restrict__ btot, int nblk)
{
    __shared__ int ssum[256];
    const int b = blockIdx.x, t = threadIdx.x;
    const int c = (t < nblk) ? (int)cnts[b * nblk + t] : 0;
    ssum[t] = c;
    __syncthreads();
    for (int off = 1; off < 256; off <<= 1) {
        int v = (t >= off) ? ssum[t - off] : 0;
        __syncthreads();
        ssum[t] += v;
        __syncthreads();
    }
    if (t < nblk) cnts[b * nblk + t] = (unsigned short)(ssum[t] - c);   // exclusive
    if (t == 255) btot[b] = ssum[255];
}

// ============ scan of bucket totals -> bbase (2 elems/thread; round-15 verified) ============
__global__ __launch_bounds__(1024) void scan_btot(
    const int* __restrict__ btot, int* __restrict__ bbase, int n_edges)
{
    __shared__ int ssum[1024];
    const int t = threadIdx.x;
    const int i0 = 2 * t, i1 = 2 * t + 1;
    const int v0 = (i0 < NBUCK) ? btot[i0] : 0;
    const int v1 = (i1 < NBUCK) ? btot[i1] : 0;
    const int s = v0 + v1;
    ssum[t] = s;
    __syncthreads();
    for (int off = 1; off < 1024; off <<= 1) {
        int v = (t >= off) ? ssum[t - off] : 0;
        __syncthreads();
        ssum[t] += v;
        __syncthreads();
    }
    int base = ssum[t] - s;                    // exclusive
    if (i0 < NBUCK) bbase[i0] = base;
    if (i1 < NBUCK) bbase[i1] = base + v0;
    if (t == 0) bbase[NBUCK] = n_edges;        // sentinel
}

// ============ bin via block-private segments (ushort prefixes) ============
__global__ __launch_bounds__(1024) void bin_pass2(
    const int* __restrict__ erow, const int* __restrict__ ecol,
    const float* __restrict__ eval, const unsigned short* __restrict__ cnts,
    const int* __restrict__ bbase, int2* __restrict__ cvbin,
    int n_edges, int nblk)
{
    __shared__ int cur[NBUCK];
    const int blk = blockIdx.x, t = threadIdx.x;
    for (int b = t; b < NBUCK; b += 1024)
        cur[b] = bbase[b] + (int)cnts[b * nblk + blk];
    __syncthreads();
    const int beg = blk * EDGES_PER_BLK;
    const int end = min(beg + EDGES_PER_BLK, n_edges);
    for (int i = beg + t; i < end; i += 1024) {
        int r = erow[i];
        int b = r >> 6;
        int pos = atomicAdd(&cur[b], 1);            // LDS atomic
        cvbin[pos] = make_int2(ecol[i] | ((r & 63) << 20), __float_as_int(eval[i]));
    }
}

// ============ fused: LDS counting-sort + SpMM + bias + L2 norm (round-15 verified) ============
__global__ __launch_bounds__(256) void sort_spmm(
    const int* __restrict__ bbase, const int2* __restrict__ cvbin,
    const unsigned short* __restrict__ yh, const float* __restrict__ bias,
    float* __restrict__ out)
{
    __shared__ int2 se[BCAP];          // 12 KB sorted edges
    __shared__ int  hcnt[BROWS];
    __shared__ int  scn[BROWS];
    __shared__ int  rowbeg[BROWS];
    __shared__ int  cur[BROWS];

    const int b = blockIdx.x, t = threadIdx.x;
    const int beg = bbase[b];
    const int end = bbase[b + 1];
    const int n = end - beg;
    const bool fits = (n <= BCAP);     // >16 sigma margin; safety path below

    if (t < BROWS) hcnt[t] = 0;
    __syncthreads();

    if (fits) {
        for (int i = t; i < n; i += 256)
            atomicAdd(&hcnt[(cvbin[beg + i].x >> 20) & 63], 1);
        __syncthreads();
        if (t < BROWS) scn[t] = hcnt[t];
        __syncthreads();
        for (int off = 1; off < BROWS; off <<= 1) {
            int v = (t < BROWS && t >= off) ? scn[t - off] : 0;
            __syncthreads();
            if (t < BROWS) scn[t] += v;
            __syncthreads();
        }
        if (t < BROWS) { rowbeg[t] = scn[t] - hcnt[t]; cur[t] = scn[t] - hcnt[t]; }
        __syncthreads();
        for (int i = t; i < n; i += 256) {
            int2 e = cvbin[beg + i];                       // L2-hot re-read
            int pos = atomicAdd(&cur[(e.x >> 20) & 63], 1);
            se[pos] = e;
        }
        __syncthreads();
    }

    const int sg = t >> 4, l = t & 15;
    #pragma unroll
    for (int rr = 0; rr < 4; ++rr) {
        const int r = sg + 16 * rr;                        // coalesced out writes
        const int row = b * BROWS + r;
        float4 acc = {0.f, 0.f, 0.f, 0.f};

        if (fits) {
            const int rb = rowbeg[r];
            const int re = rb + hcnt[r];
            int it = rb;
            for (; it + 3 < re; it += 4) {
                const int2 ea = se[it];
                const int2 eb = se[it + 1];
                const int2 ec = se[it + 2];
                const int2 ed = se[it + 3];
                const ushort4 xa = *reinterpret_cast<const ushort4*>(yh + (size_t)(ea.x & 0xFFFFF) * FDIM + l * 4);
                const ushort4 xb = *reinterpret_cast<const ushort4*>(yh + (size_t)(eb.x & 0xFFFFF) * FDIM + l * 4);
                const ushort4 xc = *reinterpret_cast<const ushort4*>(yh + (size_t)(ec.x & 0xFFFFF) * FDIM + l * 4);
                const ushort4 xd = *reinterpret_cast<const ushort4*>(yh + (size_t)(ed.x & 0xFFFFF) * FDIM + l * 4);
                const float va = __int_as_float(ea.y);
                const float vb = __int_as_float(eb.y);
                const float vc = __int_as_float(ec.y);
                const float vd = __int_as_float(ed.y);
                acc.x += va * bf2f(xa.x); acc.y += va * bf2f(xa.y); acc.z += va * bf2f(xa.z); acc.w += va * bf2f(xa.w);
                acc.x += vb * bf2f(xb.x); acc.y += vb * bf2f(xb.y); acc.z += vb * bf2f(xb.z); acc.w += vb * bf2f(xb.w);
                acc.x += vc * bf2f(xc.x); acc.y += vc * bf2f(xc.y); acc.z += vc * bf2f(xc.z); acc.w += vc * bf2f(xc.w);
                acc.x += vd * bf2f(xd.x); acc.y += vd * bf2f(xd.y); acc.z += vd * bf2f(xd.z); acc.w += vd * bf2f(xd.w);
            }
            for (; it < re; ++it) {
                const int2 e = se[it];
                const float v = __int_as_float(e.y);
                const ushort4 xv = *reinterpret_cast<const ushort4*>(yh + (size_t)(e.x & 0xFFFFF) * FDIM + l * 4);
                acc.x += v * bf2f(xv.x); acc.y += v * bf2f(xv.y); acc.z += v * bf2f(xv.z); acc.w += v * bf2f(xv.w);
            }
        } else {
            // safety path (never taken for this input): filter full segment from global
            for (int i = beg; i < end; ++i) {
                const int2 e = cvbin[i];
                if (((e.x >> 20) & 63) == r) {
                    const float v = __int_as_float(e.y);
                    const ushort4 xv = *reinterpret_cast<const ushort4*>(yh + (size_t)(e.x & 0xFFFFF) * FDIM + l * 4);
                    acc.x += v * bf2f(xv.x); acc.y += v * bf2f(xv.y); acc.z += v * bf2f(xv.z); acc.w += v * bf2f(xv.w);
                }
            }
        }

        const float4 bv = *reinterpret_cast<const float4*>(bias + l * 4);
        acc.x += bv.x; acc.y += bv.y; acc.z += bv.z; acc.w += bv.w;

        float p = acc.x * acc.x + acc.y * acc.y + acc.z * acc.z + acc.w * acc.w;
        #pragma unroll
        for (int off = 1; off < 16; off <<= 1)
            p += __shfl_xor(p, off);
        const float inv = 1.0f / sqrtf(p);
        acc.x *= inv; acc.y *= inv; acc.z *= inv; acc.w *= inv;

        if (row < N_NODES)
            *reinterpret_cast<float4*>(out + (size_t)row * FDIM + l * 4) = acc;
    }
}

// ============ GEMM + bias + L2 normalize (fallback epilogue; verified) ============
__global__ __launch_bounds__(256) void gemm_norm(
    float* __restrict__ io, const float* __restrict__ W,
    const float* __restrict__ bias)
{
    __shared__ float4 Wl[64][16];
    __shared__ float4 bl[16];
    __shared__ float  s[4][4][68];

    const int t = threadIdx.x;
    for (int i = t; i < 64 * 16; i += 256)
        ((float4*)Wl)[i] = ((const float4*)W)[i];
    if (t < 16) bl[t] = ((const float4*)bias)[t];

    const int wid  = t >> 6;
    const int lane = t & 63;
    const int sub  = lane >> 4;
    const int l    = lane & 15;
    const long base = (long)blockIdx.x * 16 + wid * 4;

    float4 sv = *reinterpret_cast<const float4*>(io + base * FDIM + lane * 4);
    *reinterpret_cast<float4*>(&s[wid][lane >> 4][(lane & 15) * 4]) = sv;
    __syncthreads();

    float4 acc = {0.f, 0.f, 0.f, 0.f};
    const float* srow = s[wid][sub];
    #pragma unroll
    for (int k = 0; k < FDIM; ++k) {
        const float a = srow[k];
        const float4 w = Wl[k][l];
        acc.x += a * w.x; acc.y += a * w.y; acc.z += a * w.z; acc.w += a * w.w;
    }
    const float4 b = bl[l];
    acc.x += b.x; acc.y += b.y; acc.z += b.z; acc.w += b.w;

    float p = acc.x*acc.x + acc.y*acc.y + acc.z*acc.z + acc.w*acc.w;
    #pragma unroll
    for (int off = 1; off < 16; off <<= 1)
        p += __shfl_xor(p, off);
    const float inv = 1.0f / sqrtf(p);
    acc.x *= inv; acc.y *= inv; acc.z *= inv; acc.w *= inv;

    *reinterpret_cast<float4*>(io + (base + sub) * FDIM + l * 4) = acc;
}

extern "C" void kernel_launch(void* const* d_in, const int* in_sizes, int n_in,
                              void* d_out, int out_size, void* d_ws, size_t ws_size,
                              hipStream_t stream) {
    const float* x    = (const float*)d_in[0];
    const int*   erow = (const int*)d_in[1];
    const int*   ecol = (const int*)d_in[2];
    const float* eval = (const float*)d_in[3];
    const float* W    = (const float*)d_in[4];
    const float* bias = (const float*)d_in[5];
    float* out = (float*)d_out;
    const int n_edges = in_sizes[1];

    const int nblk = (n_edges + EDGES_PER_BLK - 1) / EDGES_PER_BLK;   // 196
    const size_t need_bf16 = (size_t)WS_XH_OFF + (size_t)N_NODES * FDIM * sizeof(short);
    const bool cnts_fit =
        (size_t)NBUCK * nblk * sizeof(unsigned short) <= WS_BBASE_OFF
        && nblk <= 256 && EDGES_PER_BLK <= 65535;

    if (ws_size >= need_bf16 && cnts_fit) {
        unsigned short* cnts = (unsigned short*)d_ws;
        int*  bbase  = (int*)((char*)d_ws + WS_BBASE_OFF);
        int*  btot   = (int*)((char*)d_ws + WS_BTOT_OFF);
        int2* cvbin  = (int2*)((char*)d_ws + WS_CV_OFF);
        unsigned short* yh = (unsigned short*)((char*)d_ws + WS_XH_OFF);

        gemm_xw<<<N_NODES / 16, 256, 0, stream>>>(x, W, yh);
        count_blocks<<<nblk, 1024, 0, stream>>>(erow, cnts, n_edges, nblk);
        scan_within_bucket<<<NBUCK, 256, 0, stream>>>(cnts, btot, nblk);
        scan_btot<<<1, 1024, 0, stream>>>(btot, bbase, n_edges);
        bin_pass2<<<nblk, 1024, 0, stream>>>(erow, ecol, eval, cnts, bbase, cvbin,
                                             n_edges, nblk);
        sort_spmm<<<NBUCK, 256, 0, stream>>>(bbase, cvbin, yh, bias, out);
    } else {
        hipMemsetAsync(out, 0, (size_t)N_NODES * FDIM * sizeof(float), stream);
        long threads = (long)n_edges * 16;
        spmm_atomic<<<(int)((threads + 255) / 256), 256, 0, stream>>>(
            x, erow, ecol, eval, out, n_edges);
        gemm_norm<<<N_NODES / 16, 256, 0, stream>>>(out, W, bias);
    }
}